// Round 3
// baseline (5243.148 us; speedup 1.0000x reference)
//
#include <hip/hip_runtime.h>
#include <hip/hip_bf16.h>

#define T_STEPS 4
#define N 4096
#define E 65536
#define XD 256
#define HD 256
#define ZD 64

typedef __hip_bfloat16 bf16;

__device__ __forceinline__ float b2f(bf16 v){ return __bfloat162float(v); }
__device__ __forceinline__ bf16 f2b(float v){ return __float2bfloat16(v); }
__device__ __forceinline__ float splus(float x){ return (x > 20.f) ? x : log1pf(expf(x)); }
__device__ __forceinline__ float sigm(float x){ return 1.f/(1.f + expf(-x)); }

// dispatched input load / output store: f==1 -> float32 data, f==0 -> bf16 data
__device__ __forceinline__ float ldI(const void* p, size_t i, int f){
  return f ? ((const float*)p)[i] : b2f(((const bf16*)p)[i]);
}
__device__ __forceinline__ void stO(void* p, size_t i, float v, int f){
  if (f) ((float*)p)[i] = v; else ((bf16*)p)[i] = f2b(v);
}

// ---------------- dtype probe ----------------
// fp32 data read as bf16: even elements are mantissa garbage with uniform exponent
// -> ~25% of the first 256 "bf16" values have |v| >= 2^7. Real bf16 N(0,1) x: none.
__global__ void detect_k(const void* __restrict__ x, int* __restrict__ dfp){
  if (threadIdx.x == 0){
    const unsigned short* u = (const unsigned short*)x;
    int big = 0;
    for (int i = 0; i < 256; i++){
      int e = (u[i] >> 7) & 0xFF;
      if (e >= 134) big++;
    }
    *dfp = (big > 16) ? 1 : 0;
  }
}

// ---------------- setup kernels ----------------
__global__ void zero_f32_k(float* p){ p[threadIdx.x] = 0.f; }

__global__ __launch_bounds__(256) void zero_i32_k(int* p, int n){
  int i = blockIdx.x*256 + threadIdx.x; if (i < n) p[i] = 0;
}

__global__ __launch_bounds__(256) void ld_copy_k(const void* __restrict__ a, float* __restrict__ b,
                                                 int n, const int* __restrict__ dfp){
  int f = *dfp;
  int i = blockIdx.x*256 + threadIdx.x; if (i < n) b[i] = ldI(a, i, f);
}

__global__ __launch_bounds__(256) void count_deg_k(const int* __restrict__ ei, int* __restrict__ deg){
  int idx = blockIdx.x*256 + threadIdx.x;     // T*E total
  int t = idx >> 16, e = idx & (E-1);
  int dst = ei[(size_t)t*2*E + E + e] & (N-1);
  atomicAdd(&deg[t*N + dst], 1);
}

__global__ __launch_bounds__(256) void scan_k(const int* __restrict__ deg, int* __restrict__ offs,
                                              float* __restrict__ dinv){
  int t = blockIdx.x, tid = threadIdx.x;
  const int* dg = deg + t*N;
  int* of = offs + t*(N+1);
  __shared__ int sh[256];
  int base = tid*16;
  int loc[16]; int s = 0;
  #pragma unroll
  for (int i = 0; i < 16; i++){ loc[i] = s; s += dg[base+i]; }
  sh[tid] = s;
  __syncthreads();
  for (int o = 1; o < 256; o <<= 1){
    int v = (tid >= o) ? sh[tid-o] : 0;
    __syncthreads();
    sh[tid] += v;
    __syncthreads();
  }
  int pre = (tid == 0) ? 0 : sh[tid-1];
  #pragma unroll
  for (int i = 0; i < 16; i++) of[base+i] = pre + loc[i];
  if (tid == 255) of[N] = sh[255];
  #pragma unroll
  for (int i = 0; i < 16; i++) dinv[t*N + base + i] = rsqrtf(1.f + (float)dg[base+i]);
}

__global__ __launch_bounds__(256) void init_cursor_k(int* __restrict__ cur, const int* __restrict__ offs){
  int idx = blockIdx.x*256 + threadIdx.x;     // T*N
  int t = idx >> 12, n = idx & (N-1);
  cur[idx] = offs[t*(N+1) + n];
}

__global__ __launch_bounds__(256) void scatter_k(const int* __restrict__ ei, int* __restrict__ cur,
        int* __restrict__ srcs, float* __restrict__ enorm, const float* __restrict__ dinv){
  int idx = blockIdx.x*256 + threadIdx.x;     // T*E
  int t = idx >> 16, e = idx & (E-1);
  int s = ei[(size_t)t*2*E + e] & (N-1);
  int d = ei[(size_t)t*2*E + E + e] & (N-1);
  int p = atomicAdd(&cur[t*N + d], 1);
  if (p >= 0 && p < E){
    srcs[(size_t)t*E + p] = s;
    enorm[(size_t)t*E + p] = dinv[t*N + s] * dinv[t*N + d];
  }
}

__global__ __launch_bounds__(256) void adj_sum_k(const void* __restrict__ adj, float* __restrict__ scal,
                                                 const int* __restrict__ dfp){
  int f = *dfp;
  int t = blockIdx.y, tid = threadIdx.x;
  size_t aoff = (size_t)t*N*N;
  float s = 0.f;
  for (size_t i = (size_t)blockIdx.x*256 + tid; i < (size_t)N*N; i += 262144)
    s += ldI(adj, aoff + i, f);
  __shared__ float red[256];
  red[tid] = s; __syncthreads();
  for (int o = 128; o > 0; o >>= 1){ if (tid < o) red[tid] += red[tid+o]; __syncthreads(); }
  if (tid == 0) atomicAdd(&scal[t], red[0]);
}

// ---------------- GEMM: C[N x M] = A[N x K] * W[K x M] (+accum)(+bias)(+relu) ----------------
// 64x64 tiles, 256 threads, 4x4 per thread. A: amode 0 = f32 workspace, 1 = input (dispatch).
// W/bias: inputs (dispatch). C: f32 workspace.
__global__ __launch_bounds__(256) void gemm_k(const void* __restrict__ A, int amode, size_t aoff, int lda,
    const void* __restrict__ W, size_t woff, int ldw,
    float* __restrict__ C, int ldc, int K,
    const void* __restrict__ bias, int act, int accum, const int* __restrict__ dfp){
  int f = *dfp;
  __shared__ float As[16*68];
  __shared__ float Ws[16*64];
  int tid = threadIdx.x;
  int row0 = blockIdx.y*64, col0 = blockIdx.x*64;
  int tx = tid & 15, ty = tid >> 4;
  float acc[4][4] = {};
  for (int k0 = 0; k0 < K; k0 += 16){
    #pragma unroll
    for (int i = 0; i < 4; i++){
      int ii = tid + i*256; int r = ii >> 4, kk = ii & 15;
      size_t idx = aoff + (size_t)(row0+r)*lda + k0 + kk;
      As[kk*68 + r] = (amode == 0) ? ((const float*)A)[idx] : ldI(A, idx, f);
    }
    #pragma unroll
    for (int i = 0; i < 4; i++){
      int ii = tid + i*256; int kk = ii >> 6, c = ii & 63;
      Ws[kk*64 + c] = ldI(W, woff + (size_t)(k0+kk)*ldw + col0 + c, f);
    }
    __syncthreads();
    #pragma unroll
    for (int kk = 0; kk < 16; kk++){
      float ra[4], rb[4];
      #pragma unroll
      for (int q = 0; q < 4; q++) ra[q] = As[kk*68 + ty*4 + q];
      #pragma unroll
      for (int q = 0; q < 4; q++) rb[q] = Ws[kk*64 + tx*4 + q];
      #pragma unroll
      for (int p = 0; p < 4; p++)
        #pragma unroll
        for (int q = 0; q < 4; q++) acc[p][q] += ra[p]*rb[q];
    }
    __syncthreads();
  }
  #pragma unroll
  for (int p = 0; p < 4; p++){
    int r = row0 + ty*4 + p;
    #pragma unroll
    for (int q = 0; q < 4; q++){
      int c = col0 + tx*4 + q;
      size_t off = (size_t)r*ldc + c;
      float v = acc[p][q];
      if (accum) v += C[off];
      if (bias)  v += ldI(bias, c, f);
      if (act == 1) v = fmaxf(v, 0.f);
      C[off] = v;
    }
  }
}

// ---------------- GCN aggregation: one block per dst node, one col per thread ----------------
__global__ __launch_bounds__(256) void gcn_agg_k(const float* __restrict__ G, int ld,
    float* __restrict__ outp, int ldo, int M,
    const int* __restrict__ offs, const int* __restrict__ srcs,
    const float* __restrict__ enorm, const float* __restrict__ dinv,
    const void* __restrict__ bias, int act, const int* __restrict__ dfp){
  int f = *dfp;
  int n = blockIdx.x, c = threadIdx.x;
  int e0 = offs[n], e1 = offs[n+1];
  float d2 = dinv[n]*dinv[n];
  float acc = 0.f;
  if (c < M) acc = d2 * G[(size_t)n*ld + c];
  for (int e = e0; e < e1; e++){
    int s = srcs[e] & (N-1);
    float nm = enorm[e];
    if (c < M) acc += nm * G[(size_t)s*ld + c];
  }
  if (c < M){
    float v = acc;
    if (bias) v += ldI(bias, c, f);
    if (act == 1) v = fmaxf(v, 0.f);
    outp[(size_t)n*ldo + c] = v;
  }
}

// ---------------- fused dual-GCN aggregation for GRU gates (M = 256) ----------------
// mode 0: z = sig(agg(G1)+agg(G2))               -> outv
// mode 1: rh = sig(agg(G1)+agg(G2)) * hbuf       -> outv
// mode 2: h' = z*hbuf + (1-z)*tanh(agg(G1)+agg(G2)) -> hbuf (+out at ooff)
__global__ __launch_bounds__(256) void gcn_agg2_k(const float* __restrict__ G1,
    const float* __restrict__ G2,
    const int* __restrict__ offs, const int* __restrict__ srcs,
    const float* __restrict__ enorm, const float* __restrict__ dinv,
    const float* __restrict__ zgate, float* __restrict__ hbuf,
    float* __restrict__ outv, void* __restrict__ outg, size_t ooff,
    int mode, const int* __restrict__ dfp){
  int f = *dfp;
  int n = blockIdx.x, c = threadIdx.x;
  int e0 = offs[n], e1 = offs[n+1];
  float d2 = dinv[n]*dinv[n];
  size_t base = (size_t)n*HD + c;
  float a1 = d2 * G1[base];
  float a2 = d2 * G2[base];
  for (int e = e0; e < e1; e++){
    int s = srcs[e] & (N-1);
    float nm = enorm[e];
    a1 += nm * G1[(size_t)s*HD + c];
    a2 += nm * G2[(size_t)s*HD + c];
  }
  float sum = a1 + a2;
  if (mode == 0){
    outv[base] = sigm(sum);
  } else if (mode == 1){
    outv[base] = sigm(sum) * hbuf[base];
  } else {
    float z = zgate[base];
    float hv = hbuf[base];
    float v = z*hv + (1.f - z)*tanhf(sum);
    hbuf[base] = v;
    if (outg) stO(outg, ooff + base, v, f);
  }
}

// ---------------- per-step small kernels ----------------
__global__ __launch_bounds__(256) void enc_post_k(float* __restrict__ ms, const void* __restrict__ mb,
    const void* __restrict__ sb, const void* __restrict__ eps, size_t eoff,
    float* __restrict__ z, void* __restrict__ outg, size_t ooff, const int* __restrict__ dfp){
  int f = *dfp;
  int idx = blockIdx.x*256 + threadIdx.x;   // N*ZD
  int n = idx >> 6, d = idx & 63;
  float mean = ms[n*128 + d] + ldI(mb, d, f);
  float sd = splus(ms[n*128 + 64 + d] + ldI(sb, d, f));
  ms[n*128 + d] = mean;
  ms[n*128 + 64 + d] = sd;
  z[idx] = ldI(eps, eoff + idx, f) * sd + mean;
  stO(outg, ooff + idx, mean, f);
}

__global__ __launch_bounds__(256) void prior_post_kld_k(const float* __restrict__ pms,
    const float* __restrict__ ms, void* __restrict__ outg, size_t ooff,
    float* __restrict__ kacc, const int* __restrict__ dfp){
  int f = *dfp;
  int idx = blockIdx.x*256 + threadIdx.x;   // N*ZD
  int tid = threadIdx.x;
  int n = idx >> 6, d = idx & 63;
  float pm = pms[n*128 + d];
  float ps = splus(pms[n*128 + 64 + d]);
  float em = ms[n*128 + d];
  float es = ms[n*128 + 64 + d];
  float s1 = es + 1e-10f, s2 = ps + 1e-10f;
  float dm = em - pm;
  float el = 2.f*(logf(s2) - logf(s1)) - (s1*s1 + dm*dm)/(s2*s2) + 1.f;
  stO(outg, ooff + idx, pm, f);
  __shared__ float red[256];
  red[tid] = el; __syncthreads();
  for (int o = 128; o > 0; o >>= 1){ if (tid < o) red[tid] += red[tid+o]; __syncthreads(); }
  if (tid == 0) atomicAdd(kacc, red[0] * (0.5f/((float)N*(float)ZD)));
}

__global__ __launch_bounds__(256) void dec_nll_k(const float* __restrict__ z, const void* __restrict__ a,
    size_t aoff, const float* __restrict__ tsum, float* __restrict__ nll_acc,
    const int* __restrict__ dfp){
  int f = *dfp;
  __shared__ float zi[64][65];
  __shared__ float zj[64][65];
  __shared__ float red[256];
  int tid = threadIdx.x;
  int i0 = blockIdx.y*64, j0 = blockIdx.x*64;
  #pragma unroll
  for (int k = 0; k < 16; k++){
    int ii = tid + k*256; int r = ii >> 6, c = ii & 63;
    zi[r][c] = z[(size_t)(i0+r)*ZD + c];
    zj[r][c] = z[(size_t)(j0+r)*ZD + c];
  }
  __syncthreads();
  int tx = tid & 15, ty = tid >> 4;
  float acc[4][4] = {};
  #pragma unroll
  for (int d = 0; d < 64; d++){
    float ra[4], rb[4];
    #pragma unroll
    for (int q = 0; q < 4; q++) ra[q] = zi[ty*4+q][d];
    #pragma unroll
    for (int q = 0; q < 4; q++) rb[q] = zj[tx*4+q][d];
    #pragma unroll
    for (int p = 0; p < 4; p++)
      #pragma unroll
      for (int q = 0; q < 4; q++) acc[p][q] += ra[p]*rb[q];
  }
  float ts = *tsum;
  const float NNf = 16777216.f;
  float posw = (NNf - ts)/ts;
  float local = 0.f;
  #pragma unroll
  for (int p = 0; p < 4; p++){
    int i = i0 + ty*4 + p;
    #pragma unroll
    for (int q = 0; q < 4; q++){
      int j = j0 + tx*4 + q;
      float dec = sigm(acc[p][q]);
      float av = ldI(a, aoff + (size_t)i*N + j, f);
      float bce = (1.f - av)*splus(dec);
      if (av != 0.f) bce += posw*av*splus(-dec);
      local += bce;
    }
  }
  red[tid] = local; __syncthreads();
  for (int o = 128; o > 0; o >>= 1){ if (tid < o) red[tid] += red[tid+o]; __syncthreads(); }
  if (tid == 0) atomicAdd(nll_acc, red[0] * 0.5f/(NNf - ts));
}

__global__ void finalize_k(const float* __restrict__ scal, void* __restrict__ outg,
                           const int* __restrict__ dfp){
  int f = *dfp;
  if (threadIdx.x == 0) stO(outg, 0, scal[4], f);
  if (threadIdx.x == 1) stO(outg, 1, scal[5], f);
}

// ---------------- host ----------------
extern "C" void kernel_launch(void* const* d_in, const int* in_sizes, int n_in,
                              void* d_out, int out_size, void* d_ws, size_t ws_size,
                              hipStream_t stream){
  const void* x           = d_in[0];
  const int*  ei          = (const int*)d_in[1];
  const void* adj         = d_in[2];
  const void* eps         = d_in[3];
  const void* h0          = d_in[4];
  const void* phi_x_w     = d_in[5];
  const void* phi_x_b     = d_in[6];
  const void* phi_z_w     = d_in[7];
  const void* phi_z_b     = d_in[8];
  const void* enc_w       = d_in[9];
  const void* enc_b       = d_in[10];
  const void* enc_mean_w  = d_in[11];
  const void* enc_mean_b  = d_in[12];
  const void* enc_std_w   = d_in[13];
  const void* enc_std_b   = d_in[14];
  const void* prior_w     = d_in[15];
  const void* prior_b     = d_in[16];
  const void* prior_mean_w= d_in[17];
  const void* prior_mean_b= d_in[18];
  const void* prior_std_w = d_in[19];
  const void* prior_std_b = d_in[20];
  const void* gru_xz_w    = d_in[21];
  const void* gru_hz_w    = d_in[22];
  const void* gru_xr_w    = d_in[23];
  const void* gru_hr_w    = d_in[24];
  const void* gru_xh_w    = d_in[25];
  const void* gru_hh_w    = d_in[26];

  // bump allocator over d_ws (~35.5 MB total)
  char* wp = (char*)d_ws;
  auto alloc = [&](size_t bytes){ void* p = (void*)wp; wp += (bytes + 255) & ~(size_t)255; return p; };
  float* scal  = (float*)alloc(64*sizeof(float));          // [0..3]=tsum per t, [4]=kld, [5]=nll
  int*   dflag = (int*)  alloc(256);
  float* dinv  = (float*)alloc((size_t)T_STEPS*N*4);
  int*   offs  = (int*)  alloc((size_t)T_STEPS*(N+1)*4);
  int*   srcs  = (int*)  alloc((size_t)T_STEPS*E*4);
  float* enorm = (float*)alloc((size_t)T_STEPS*E*4);
  int*   deg   = (int*)  alloc((size_t)T_STEPS*N*4);       // reused as scatter cursor
  float* h_prev= (float*)alloc((size_t)N*HD*4);
  float* phiX  = (float*)alloc((size_t)N*HD*4);
  float* phiZ  = (float*)alloc((size_t)N*HD*4);
  float* Tb1   = (float*)alloc((size_t)N*HD*4);            // enc_t, later r*h
  float* Tb2   = (float*)alloc((size_t)N*HD*4);            // prior_t, later z_g
  float* zbuf  = (float*)alloc((size_t)N*ZD*4);
  float* ms    = (float*)alloc((size_t)N*128*4);           // enc [mean|std]
  float* pms   = (float*)alloc((size_t)N*128*4);           // prior [mean|stdpre]
  float* Gs1   = (float*)alloc((size_t)N*HD*4);            // GEMM staging
  float* Gs2   = (float*)alloc((size_t)N*HD*4);

  detect_k<<<1,64,0,stream>>>(x, dflag);
  zero_f32_k<<<1,64,0,stream>>>(scal);
  zero_i32_k<<<(T_STEPS*N)/256,256,0,stream>>>(deg, T_STEPS*N);
  count_deg_k<<<(T_STEPS*E)/256,256,0,stream>>>(ei, deg);
  scan_k<<<T_STEPS,256,0,stream>>>(deg, offs, dinv);
  init_cursor_k<<<(T_STEPS*N)/256,256,0,stream>>>(deg, offs);
  scatter_k<<<(T_STEPS*E)/256,256,0,stream>>>(ei, deg, srcs, enorm, dinv);
  adj_sum_k<<<dim3(1024,T_STEPS),256,0,stream>>>(adj, scal, dflag);
  ld_copy_k<<<(N*HD)/256,256,0,stream>>>(h0, h_prev, N*HD, dflag);

  auto gemm = [&](const void* A, int amode, size_t aoff, int lda,
                  const void* W, size_t woff, int ldw, float* C, int ldc,
                  int M, int K, const void* bias, int act, int accum){
    dim3 g(M/64, N/64);
    gemm_k<<<g,256,0,stream>>>(A, amode, aoff, lda, W, woff, ldw, C, ldc, K, bias, act, accum, dflag);
  };
  auto agg = [&](const float* G, int ld, float* o, int ldo, int M, int t,
                 const void* bias, int act){
    gcn_agg_k<<<N,256,0,stream>>>(G, ld, o, ldo, M, offs + t*(N+1), srcs + (size_t)t*E,
                                  enorm + (size_t)t*E, dinv + t*N, bias, act, dflag);
  };
  auto agg2 = [&](int t, const float* zg, float* hb, float* ov, void* og, size_t ooff, int mode){
    gcn_agg2_k<<<N,256,0,stream>>>(Gs1, Gs2, offs + t*(N+1), srcs + (size_t)t*E,
                                   enorm + (size_t)t*E, dinv + t*N, zg, hb, ov, og, ooff, mode, dflag);
  };

  const size_t OUT_EM = 2;
  const size_t OUT_PM = 2 + (size_t)T_STEPS*N*ZD;
  const size_t OUT_H  = 2 + (size_t)2*T_STEPS*N*ZD;

  for (int t = 0; t < T_STEPS; t++){
    // phi_x = relu(x_t @ phi_x_w + b)
    gemm(x, 1, (size_t)t*N*XD, XD, phi_x_w, 0, HD, phiX, HD, HD, XD, phi_x_b, 1, 0);
    // enc GCN: pre = [phi_x | h] @ enc_w  (split-K), aggregate, +b, relu -> Tb1
    gemm(phiX,   0, 0, HD, enc_w, 0,             HD, Gs1, HD, HD, HD, nullptr, 0, 0);
    gemm(h_prev, 0, 0, HD, enc_w, (size_t)HD*HD, HD, Gs1, HD, HD, HD, nullptr, 0, 1);
    agg(Gs1, HD, Tb1, HD, HD, t, enc_b, 1);
    // enc mean/std GCNs (combined 128-wide staging)
    gemm(Tb1, 0, 0, HD, enc_mean_w, 0, ZD, Gs1,    128, ZD, HD, nullptr, 0, 0);
    gemm(Tb1, 0, 0, HD, enc_std_w,  0, ZD, Gs1+64, 128, ZD, HD, nullptr, 0, 0);
    agg(Gs1, 128, ms, 128, 128, t, nullptr, 0);
    enc_post_k<<<(N*ZD)/256,256,0,stream>>>(ms, enc_mean_b, enc_std_b,
        eps, (size_t)t*N*ZD, zbuf, d_out, OUT_EM + (size_t)t*N*ZD, dflag);
    // prior MLPs
    gemm(h_prev, 0, 0, HD, prior_w, 0, HD, Tb2, HD, HD, HD, prior_b, 1, 0);
    gemm(Tb2, 0, 0, HD, prior_mean_w, 0, ZD, pms,    128, ZD, HD, prior_mean_b, 0, 0);
    gemm(Tb2, 0, 0, HD, prior_std_w,  0, ZD, pms+64, 128, ZD, HD, prior_std_b,  0, 0);
    prior_post_kld_k<<<(N*ZD)/256,256,0,stream>>>(pms, ms, d_out,
        OUT_PM + (size_t)t*N*ZD, scal + 4, dflag);
    // phi_z = relu(z @ phi_z_w + b)
    gemm(zbuf, 0, 0, ZD, phi_z_w, 0, HD, phiZ, HD, HD, ZD, phi_z_b, 1, 0);
    // decode + NLL
    dec_nll_k<<<dim3(64,64),256,0,stream>>>(zbuf, adj, (size_t)t*N*N, scal + t, scal + 5, dflag);
    // GRU z gate: sig(gcn([phiX|phiZ]@xz) + gcn(h@hz)) -> Tb2
    gemm(phiX, 0, 0, HD, gru_xz_w, 0,             HD, Gs1, HD, HD, HD, nullptr, 0, 0);
    gemm(phiZ, 0, 0, HD, gru_xz_w, (size_t)HD*HD, HD, Gs1, HD, HD, HD, nullptr, 0, 1);
    gemm(h_prev, 0, 0, HD, gru_hz_w, 0, HD, Gs2, HD, HD, HD, nullptr, 0, 0);
    agg2(t, nullptr, h_prev, Tb2, nullptr, 0, 0);
    // GRU r gate: rh = sig(gcn(gin@xr) + gcn(h@hr)) * h -> Tb1
    gemm(phiX, 0, 0, HD, gru_xr_w, 0,             HD, Gs1, HD, HD, HD, nullptr, 0, 0);
    gemm(phiZ, 0, 0, HD, gru_xr_w, (size_t)HD*HD, HD, Gs1, HD, HD, HD, nullptr, 0, 1);
    gemm(h_prev, 0, 0, HD, gru_hr_w, 0, HD, Gs2, HD, HD, HD, nullptr, 0, 0);
    agg2(t, nullptr, h_prev, Tb1, nullptr, 0, 1);
    // candidate + update: h = z*h + (1-z)*tanh(gcn(gin@xh) + gcn(rh@hh))
    gemm(phiX, 0, 0, HD, gru_xh_w, 0,             HD, Gs1, HD, HD, HD, nullptr, 0, 0);
    gemm(phiZ, 0, 0, HD, gru_xh_w, (size_t)HD*HD, HD, Gs1, HD, HD, HD, nullptr, 0, 1);
    gemm(Tb1, 0, 0, HD, gru_hh_w, 0, HD, Gs2, HD, HD, HD, nullptr, 0, 0);
    agg2(t, Tb2, h_prev, nullptr, (t == T_STEPS-1) ? d_out : (void*)nullptr, OUT_H, 2);
  }
  finalize_k<<<1,64,0,stream>>>(scal, d_out, dflag);
}

// Round 4
// 3104.883 us; speedup vs baseline: 1.6887x; 1.6887x over previous
//
#include <hip/hip_runtime.h>
#include <hip/hip_bf16.h>

#define T_STEPS 4
#define N 4096
#define E 65536
#define XD 256
#define HD 256
#define ZD 64

typedef __hip_bfloat16 bf16;

__device__ __forceinline__ float b2f(bf16 v){ return __bfloat162float(v); }
__device__ __forceinline__ bf16 f2b(float v){ return __float2bfloat16(v); }
__device__ __forceinline__ float splus(float x){ return (x > 20.f) ? x : log1pf(expf(x)); }
__device__ __forceinline__ float sigm(float x){ return 1.f/(1.f + expf(-x)); }

// dispatched input load / output store: f==1 -> float32 data, f==0 -> bf16 data
__device__ __forceinline__ float ldI(const void* p, size_t i, int f){
  return f ? ((const float*)p)[i] : b2f(((const bf16*)p)[i]);
}
__device__ __forceinline__ void stO(void* p, size_t i, float v, int f){
  if (f) ((float*)p)[i] = v; else ((bf16*)p)[i] = f2b(v);
}
__device__ __forceinline__ void st(float* p, float v){ *p = v; }
__device__ __forceinline__ void st(bf16* p, float v){ *p = f2b(v); }

// ---------------- dtype probe ----------------
__global__ void detect_k(const void* __restrict__ x, int* __restrict__ dfp){
  if (threadIdx.x == 0){
    const unsigned short* u = (const unsigned short*)x;
    int big = 0;
    for (int i = 0; i < 256; i++){
      int e = (u[i] >> 7) & 0xFF;
      if (e >= 134) big++;
    }
    *dfp = (big > 16) ? 1 : 0;
  }
}

// ---------------- setup kernels ----------------
__global__ void zero_f32_k(float* p){ p[threadIdx.x] = 0.f; }

__global__ __launch_bounds__(256) void zero_i32_k(int* p, int n){
  int i = blockIdx.x*256 + threadIdx.x; if (i < n) p[i] = 0;
}

__global__ __launch_bounds__(256) void ld_copy_k(const void* __restrict__ a, float* __restrict__ b,
                                                 int n, const int* __restrict__ dfp){
  int f = *dfp;
  int i = blockIdx.x*256 + threadIdx.x; if (i < n) b[i] = ldI(a, i, f);
}

__global__ __launch_bounds__(256) void count_deg_k(const int* __restrict__ ei, int* __restrict__ deg){
  int idx = blockIdx.x*256 + threadIdx.x;     // T*E total
  int t = idx >> 16, e = idx & (E-1);
  int dst = ei[(size_t)t*2*E + E + e] & (N-1);
  atomicAdd(&deg[t*N + dst], 1);
}

__global__ __launch_bounds__(256) void scan_k(const int* __restrict__ deg, int* __restrict__ offs,
                                              float* __restrict__ dinv){
  int t = blockIdx.x, tid = threadIdx.x;
  const int* dg = deg + t*N;
  int* of = offs + t*(N+1);
  __shared__ int sh[256];
  int base = tid*16;
  int loc[16]; int s = 0;
  #pragma unroll
  for (int i = 0; i < 16; i++){ loc[i] = s; s += dg[base+i]; }
  sh[tid] = s;
  __syncthreads();
  for (int o = 1; o < 256; o <<= 1){
    int v = (tid >= o) ? sh[tid-o] : 0;
    __syncthreads();
    sh[tid] += v;
    __syncthreads();
  }
  int pre = (tid == 0) ? 0 : sh[tid-1];
  #pragma unroll
  for (int i = 0; i < 16; i++) of[base+i] = pre + loc[i];
  if (tid == 255) of[N] = sh[255];
  #pragma unroll
  for (int i = 0; i < 16; i++) dinv[t*N + base + i] = rsqrtf(1.f + (float)dg[base+i]);
}

__global__ __launch_bounds__(256) void init_cursor_k(int* __restrict__ cur, const int* __restrict__ offs){
  int idx = blockIdx.x*256 + threadIdx.x;     // T*N
  int t = idx >> 12, n = idx & (N-1);
  cur[idx] = offs[t*(N+1) + n];
}

__global__ __launch_bounds__(256) void scatter_k(const int* __restrict__ ei, int* __restrict__ cur,
        int* __restrict__ srcs, float* __restrict__ enorm, const float* __restrict__ dinv){
  int idx = blockIdx.x*256 + threadIdx.x;     // T*E
  int t = idx >> 16, e = idx & (E-1);
  int s = ei[(size_t)t*2*E + e] & (N-1);
  int d = ei[(size_t)t*2*E + E + e] & (N-1);
  int p = atomicAdd(&cur[t*N + d], 1);
  if (p >= 0 && p < E){
    srcs[(size_t)t*E + p] = s;
    enorm[(size_t)t*E + p] = dinv[t*N + s] * dinv[t*N + d];
  }
}

__global__ __launch_bounds__(256) void adj_sum_k(const void* __restrict__ adj, float* __restrict__ scal,
                                                 const int* __restrict__ dfp){
  int f = *dfp;
  int t = blockIdx.y, tid = threadIdx.x;
  size_t aoff = (size_t)t*N*N;
  float s = 0.f;
  for (size_t i = (size_t)blockIdx.x*256 + tid; i < (size_t)N*N; i += 262144)
    s += ldI(adj, aoff + i, f);
  __shared__ float red[256];
  red[tid] = s; __syncthreads();
  for (int o = 128; o > 0; o >>= 1){ if (tid < o) red[tid] += red[tid+o]; __syncthreads(); }
  if (tid == 0) atomicAdd(&scal[t], red[0]);
}

// ---------------- universal GEMM ----------------
// C[N x M] = [A1 (k<K1) | A2 (k>=K1)] @ W_sel(col) + bias_sel, opt relu.
// W_sel: col block c0 picks W{0,1,2} by c0/wblk; W is [K x wblk] row-major.
// amode: 0 = f32 ws, 1 = input (dflag dispatch), 2 = bf16 ws. cmode: 0 = f32 C, 1 = bf16 C.
__global__ __launch_bounds__(256) void gemm_k(
    const void* __restrict__ A1, int am1, size_t ao1, int lda1,
    const void* __restrict__ A2, int am2, size_t ao2, int lda2,
    int K1, int K,
    const void* __restrict__ W0, const void* __restrict__ W1, const void* __restrict__ W2,
    int wblk, void* __restrict__ C, int ldc, int cmode,
    const void* __restrict__ b0, const void* __restrict__ b1, const void* __restrict__ b2,
    int act, const int* __restrict__ dfp){
  int f = *dfp;
  __shared__ float As[16*68];   // [k][row], stride 68 (16B-aligned rows of 4)
  __shared__ float Ws[16*64];   // [k][col]
  int tid = threadIdx.x;
  int row0 = blockIdx.y*64, col0 = blockIdx.x*64;
  int widx = col0 / wblk, wcol = col0 % wblk;
  const void* W  = (widx == 0) ? W0 : ((widx == 1) ? W1 : W2);
  const void* bs = (widx == 0) ? b0 : ((widx == 1) ? b1 : b2);
  int tx = tid & 15, ty = tid >> 4;
  float acc[4][4] = {};
  for (int k0 = 0; k0 < K; k0 += 16){
    const void* A; int am; size_t ao; int lda; int kb;
    if (k0 < K1){ A = A1; am = am1; ao = ao1; lda = lda1; kb = k0; }
    else        { A = A2; am = am2; ao = ao2; lda = lda2; kb = k0 - K1; }
    #pragma unroll
    for (int i = 0; i < 4; i++){
      int ii = tid + i*256; int r = ii >> 4, kk = ii & 15;
      size_t idx = ao + (size_t)(row0+r)*lda + kb + kk;
      float v;
      if (am == 0) v = ((const float*)A)[idx];
      else if (am == 2) v = b2f(((const bf16*)A)[idx]);
      else v = ldI(A, idx, f);
      As[kk*68 + r] = v;
    }
    #pragma unroll
    for (int i = 0; i < 4; i++){
      int ii = tid + i*256; int kk = ii >> 6, c = ii & 63;
      Ws[kk*64 + c] = ldI(W, (size_t)(k0+kk)*wblk + wcol + c, f);
    }
    __syncthreads();
    #pragma unroll
    for (int kk = 0; kk < 16; kk++){
      float ra[4], rb[4];
      #pragma unroll
      for (int q = 0; q < 4; q++) ra[q] = As[kk*68 + ty*4 + q];
      #pragma unroll
      for (int q = 0; q < 4; q++) rb[q] = Ws[kk*64 + tx*4 + q];
      #pragma unroll
      for (int p = 0; p < 4; p++)
        #pragma unroll
        for (int q = 0; q < 4; q++) acc[p][q] += ra[p]*rb[q];
    }
    __syncthreads();
  }
  #pragma unroll
  for (int p = 0; p < 4; p++){
    int r = row0 + ty*4 + p;
    #pragma unroll
    for (int q = 0; q < 4; q++){
      int c = tx*4 + q;
      size_t off = (size_t)r*ldc + col0 + c;
      float v = acc[p][q];
      if (bs)  v += ldI(bs, wcol + c, f);
      if (act == 1) v = fmaxf(v, 0.f);
      if (cmode) ((bf16*)C)[off] = f2b(v); else ((float*)C)[off] = v;
    }
  }
}

// ---------------- GCN aggregation: one block per dst node, one col per thread (blockDim==M) ----
template<typename TO>
__global__ void gcn_agg_k(const bf16* __restrict__ G, int ld,
    TO* __restrict__ outp, int ldo,
    const int* __restrict__ offs, const int* __restrict__ srcs,
    const float* __restrict__ enorm, const float* __restrict__ dinv,
    const void* __restrict__ bias, int act, const int* __restrict__ dfp){
  int f = *dfp;
  int n = blockIdx.x, c = threadIdx.x;
  int e0 = offs[n], e1 = offs[n+1];
  float d2 = dinv[n]*dinv[n];
  float acc = d2 * b2f(G[(size_t)n*ld + c]);
  for (int e = e0; e < e1; e++){
    int s = srcs[e] & (N-1);
    acc += enorm[e] * b2f(G[(size_t)s*ld + c]);
  }
  float v = acc;
  if (bias) v += ldI(bias, c, f);
  if (act == 1) v = fmaxf(v, 0.f);
  st(&outp[(size_t)n*ldo + c], v);
}

// ---------------- fused dual-GCN aggregation for GRU gates (blockDim = 256) ----------------
// mode 0: z = sig(agg(G1)+agg(G2))                  -> (float*)outv
// mode 1: rh = sig(agg(G1)+agg(G2)) * hbuf          -> (bf16*)outv
// mode 2: h' = z*hbuf + (1-z)*tanh(agg(G1)+agg(G2)) -> hbuf (+opt outg at ooff)
__global__ __launch_bounds__(256) void gcn_agg2_k(
    const bf16* __restrict__ G1, int ld1, const bf16* __restrict__ G2, int ld2,
    const int* __restrict__ offs, const int* __restrict__ srcs,
    const float* __restrict__ enorm, const float* __restrict__ dinv,
    const float* __restrict__ zgate, float* __restrict__ hbuf,
    void* __restrict__ outv, void* __restrict__ outg, size_t ooff,
    int mode, const int* __restrict__ dfp){
  int f = *dfp;
  int n = blockIdx.x, c = threadIdx.x;
  int e0 = offs[n], e1 = offs[n+1];
  float d2 = dinv[n]*dinv[n];
  float a1 = d2 * b2f(G1[(size_t)n*ld1 + c]);
  float a2 = d2 * b2f(G2[(size_t)n*ld2 + c]);
  for (int e = e0; e < e1; e++){
    int s = srcs[e] & (N-1);
    float nm = enorm[e];
    a1 += nm * b2f(G1[(size_t)s*ld1 + c]);
    a2 += nm * b2f(G2[(size_t)s*ld2 + c]);
  }
  float sum = a1 + a2;
  size_t base = (size_t)n*HD + c;
  if (mode == 0){
    ((float*)outv)[base] = sigm(sum);
  } else if (mode == 1){
    ((bf16*)outv)[base] = f2b(sigm(sum) * hbuf[base]);
  } else {
    float z = zgate[base];
    float hv = hbuf[base];
    float v = z*hv + (1.f - z)*tanhf(sum);
    hbuf[base] = v;
    if (outg) stO(outg, ooff + base, v, f);
  }
}

// ---------------- per-step small kernels ----------------
__global__ __launch_bounds__(256) void enc_post_k(float* __restrict__ ms, const void* __restrict__ mb,
    const void* __restrict__ sb, const void* __restrict__ eps, size_t eoff,
    float* __restrict__ z, void* __restrict__ outg, size_t ooff, const int* __restrict__ dfp){
  int f = *dfp;
  int idx = blockIdx.x*256 + threadIdx.x;   // N*ZD
  int n = idx >> 6, d = idx & 63;
  float mean = ms[n*128 + d] + ldI(mb, d, f);
  float sd = splus(ms[n*128 + 64 + d] + ldI(sb, d, f));
  ms[n*128 + d] = mean;
  ms[n*128 + 64 + d] = sd;
  z[idx] = ldI(eps, eoff + idx, f) * sd + mean;
  stO(outg, ooff + idx, mean, f);
}

__global__ __launch_bounds__(256) void prior_post_kld_k(const float* __restrict__ pms,
    const float* __restrict__ ms, void* __restrict__ outg, size_t ooff,
    float* __restrict__ kacc, const int* __restrict__ dfp){
  int f = *dfp;
  int idx = blockIdx.x*256 + threadIdx.x;   // N*ZD
  int tid = threadIdx.x;
  int n = idx >> 6, d = idx & 63;
  float pm = pms[n*128 + d];
  float ps = splus(pms[n*128 + 64 + d]);
  float em = ms[n*128 + d];
  float es = ms[n*128 + 64 + d];
  float s1 = es + 1e-10f, s2 = ps + 1e-10f;
  float dm = em - pm;
  float el = 2.f*(logf(s2) - logf(s1)) - (s1*s1 + dm*dm)/(s2*s2) + 1.f;
  stO(outg, ooff + idx, pm, f);
  __shared__ float red[256];
  red[tid] = el; __syncthreads();
  for (int o = 128; o > 0; o >>= 1){ if (tid < o) red[tid] += red[tid+o]; __syncthreads(); }
  if (tid == 0) atomicAdd(kacc, red[0] * (0.5f/((float)N*(float)ZD)));
}

// ---------------- decode + NLL (v2: transposed padded LDS, vectorized, occupancy-capped) ----
__global__ __launch_bounds__(256, 3) void dec_nll_k(const float* __restrict__ z,
    const void* __restrict__ a, size_t aoff, const float* __restrict__ tsum,
    float* __restrict__ nll_acc, const int* __restrict__ dfp){
  int f = *dfp;
  __shared__ float ziT[64*68];   // [d][row], stride 68 -> 16B-aligned float4 rows
  __shared__ float zjT[64*68];
  int tid = threadIdx.x;
  int i0 = blockIdx.y*64, j0 = blockIdx.x*64;
  #pragma unroll
  for (int k = 0; k < 16; k++){
    int ii = tid + k*256; int r = ii >> 6, d = ii & 63;
    ziT[d*68 + r] = z[(size_t)(i0+r)*ZD + d];
    zjT[d*68 + r] = z[(size_t)(j0+r)*ZD + d];
  }
  __syncthreads();
  int tx = tid & 15, ty = tid >> 4;
  float acc[4][4] = {};
  #pragma unroll 8
  for (int d = 0; d < 64; d++){
    float4 ra = *(const float4*)&ziT[d*68 + ty*4];
    float4 rb = *(const float4*)&zjT[d*68 + tx*4];
    acc[0][0] += ra.x*rb.x; acc[0][1] += ra.x*rb.y; acc[0][2] += ra.x*rb.z; acc[0][3] += ra.x*rb.w;
    acc[1][0] += ra.y*rb.x; acc[1][1] += ra.y*rb.y; acc[1][2] += ra.y*rb.z; acc[1][3] += ra.y*rb.w;
    acc[2][0] += ra.z*rb.x; acc[2][1] += ra.z*rb.y; acc[2][2] += ra.z*rb.z; acc[2][3] += ra.z*rb.w;
    acc[3][0] += ra.w*rb.x; acc[3][1] += ra.w*rb.y; acc[3][2] += ra.w*rb.z; acc[3][3] += ra.w*rb.w;
  }
  float ts = *tsum;
  const float NNf = 16777216.f;
  float posw = (NNf - ts)/ts;
  float local = 0.f;
  #pragma unroll
  for (int p = 0; p < 4; p++){
    int i = i0 + ty*4 + p;
    size_t rowoff = aoff + (size_t)i*N + j0 + tx*4;
    float av4[4];
    if (f){
      float4 v = *(const float4*)((const float*)a + rowoff);
      av4[0] = v.x; av4[1] = v.y; av4[2] = v.z; av4[3] = v.w;
    } else {
      const bf16* pb = (const bf16*)a + rowoff;
      av4[0] = b2f(pb[0]); av4[1] = b2f(pb[1]); av4[2] = b2f(pb[2]); av4[3] = b2f(pb[3]);
    }
    #pragma unroll
    for (int q = 0; q < 4; q++){
      float dec = sigm(acc[p][q]);
      float av = av4[q];
      float bce = (1.f - av)*log1pf(expf(dec));
      if (av != 0.f) bce += posw*av*log1pf(expf(-dec));
      local += bce;
    }
  }
  __syncthreads();                    // all LDS reads done before reuse
  ziT[tid] = local; __syncthreads();
  for (int o = 128; o > 0; o >>= 1){ if (tid < o) ziT[tid] += ziT[tid+o]; __syncthreads(); }
  if (tid == 0) atomicAdd(nll_acc, ziT[0] * 0.5f/(NNf - ts));
}

__global__ void finalize_k(const float* __restrict__ scal, void* __restrict__ outg,
                           const int* __restrict__ dfp){
  int f = *dfp;
  if (threadIdx.x == 0) stO(outg, 0, scal[4], f);
  if (threadIdx.x == 1) stO(outg, 1, scal[5], f);
}

// ---------------- host ----------------
extern "C" void kernel_launch(void* const* d_in, const int* in_sizes, int n_in,
                              void* d_out, int out_size, void* d_ws, size_t ws_size,
                              hipStream_t stream){
  const void* x           = d_in[0];
  const int*  ei          = (const int*)d_in[1];
  const void* adj         = d_in[2];
  const void* eps         = d_in[3];
  const void* h0          = d_in[4];
  const void* phi_x_w     = d_in[5];
  const void* phi_x_b     = d_in[6];
  const void* phi_z_w     = d_in[7];
  const void* phi_z_b     = d_in[8];
  const void* enc_w       = d_in[9];
  const void* enc_b       = d_in[10];
  const void* enc_mean_w  = d_in[11];
  const void* enc_mean_b  = d_in[12];
  const void* enc_std_w   = d_in[13];
  const void* enc_std_b   = d_in[14];
  const void* prior_w     = d_in[15];
  const void* prior_b     = d_in[16];
  const void* prior_mean_w= d_in[17];
  const void* prior_mean_b= d_in[18];
  const void* prior_std_w = d_in[19];
  const void* prior_std_b = d_in[20];
  const void* gru_xz_w    = d_in[21];
  const void* gru_hz_w    = d_in[22];
  const void* gru_xr_w    = d_in[23];
  const void* gru_hr_w    = d_in[24];
  const void* gru_xh_w    = d_in[25];
  const void* gru_hh_w    = d_in[26];

  // bump allocator over d_ws (~28 MB total)
  char* wp = (char*)d_ws;
  auto alloc = [&](size_t bytes){ void* p = (void*)wp; wp += (bytes + 255) & ~(size_t)255; return p; };
  float* scal  = (float*)alloc(64*sizeof(float));          // [0..3]=tsum per t, [4]=kld, [5]=nll
  int*   dflag = (int*)  alloc(256);
  float* dinv  = (float*)alloc((size_t)T_STEPS*N*4);
  int*   offs  = (int*)  alloc((size_t)T_STEPS*(N+1)*4);
  int*   srcs  = (int*)  alloc((size_t)T_STEPS*E*4);
  float* enorm = (float*)alloc((size_t)T_STEPS*E*4);
  int*   deg   = (int*)  alloc((size_t)T_STEPS*N*4);       // reused as scatter cursor
  float* h_prev= (float*)alloc((size_t)N*HD*4);
  bf16*  phiX  = (bf16*) alloc((size_t)N*HD*2);
  bf16*  Tb1   = (bf16*) alloc((size_t)N*HD*2);            // enc_t, later rh
  bf16*  Tb2   = (bf16*) alloc((size_t)N*HD*2);            // prior_t, later phiZ
  float* zbuf  = (float*)alloc((size_t)N*ZD*4);
  float* ms    = (float*)alloc((size_t)N*128*4);           // enc [mean|std]; + pms = z_g overlay
  float* pms   = (float*)alloc((size_t)N*128*4);           // prior [mean|stdpre]
  bf16*  Gs1   = (bf16*) alloc((size_t)N*768*2);           // GEMM staging wide
  bf16*  Gs2   = (bf16*) alloc((size_t)N*512*2);
  float* z_g   = ms;                                        // overlays ms+pms (dead by then)

  detect_k<<<1,64,0,stream>>>(x, dflag);
  zero_f32_k<<<1,64,0,stream>>>(scal);
  zero_i32_k<<<(T_STEPS*N)/256,256,0,stream>>>(deg, T_STEPS*N);
  count_deg_k<<<(T_STEPS*E)/256,256,0,stream>>>(ei, deg);
  scan_k<<<T_STEPS,256,0,stream>>>(deg, offs, dinv);
  init_cursor_k<<<(T_STEPS*N)/256,256,0,stream>>>(deg, offs);
  scatter_k<<<(T_STEPS*E)/256,256,0,stream>>>(ei, deg, srcs, enorm, dinv);
  adj_sum_k<<<dim3(1024,T_STEPS),256,0,stream>>>(adj, scal, dflag);
  ld_copy_k<<<(N*HD)/256,256,0,stream>>>(h0, h_prev, N*HD, dflag);

  // gemm(A1,am1,ao1,lda1, A2,am2,lda2, K1,K, W0,W1,W2,wblk, C,ldc,cmode, b0,b1,b2, act, M)
  auto gemm = [&](const void* A1, int am1, size_t ao1, int lda1,
                  const void* A2, int am2, int lda2, int K1, int K,
                  const void* W0, const void* W1, const void* W2, int wblk,
                  void* C, int ldc, int cmode,
                  const void* b0, const void* b1, const void* b2, int act, int M){
    dim3 g(M/64, N/64);
    gemm_k<<<g,256,0,stream>>>(A1, am1, ao1, lda1, A2, am2, 0, lda2, K1, K,
                               W0, W1, W2, wblk, C, ldc, cmode, b0, b1, b2, act, dflag);
  };
  auto agg_b = [&](const bf16* G, int ld, bf16* o, int ldo, int M, int t,
                   const void* bias, int act){
    gcn_agg_k<bf16><<<N,M,0,stream>>>(G, ld, o, ldo, offs + t*(N+1), srcs + (size_t)t*E,
                                      enorm + (size_t)t*E, dinv + t*N, bias, act, dflag);
  };
  auto agg_f = [&](const bf16* G, int ld, float* o, int ldo, int M, int t){
    gcn_agg_k<float><<<N,M,0,stream>>>(G, ld, o, ldo, offs + t*(N+1), srcs + (size_t)t*E,
                                       enorm + (size_t)t*E, dinv + t*N, nullptr, 0, dflag);
  };
  auto agg2 = [&](int t, const bf16* G1, int ld1, const bf16* G2, int ld2,
                  const float* zg, void* ov, void* og, size_t ooff, int mode){
    gcn_agg2_k<<<N,256,0,stream>>>(G1, ld1, G2, ld2, offs + t*(N+1), srcs + (size_t)t*E,
                                   enorm + (size_t)t*E, dinv + t*N, zg, h_prev, ov, og, ooff,
                                   mode, dflag);
  };

  const size_t OUT_EM = 2;
  const size_t OUT_PM = 2 + (size_t)T_STEPS*N*ZD;
  const size_t OUT_H  = 2 + (size_t)2*T_STEPS*N*ZD;

  for (int t = 0; t < T_STEPS; t++){
    // phi_x = relu(x_t @ phi_x_w + b)  -> phiX (bf16)
    gemm(x, 1, (size_t)t*N*XD, XD, nullptr, 0, 0, XD, XD,
         phi_x_w, nullptr, nullptr, HD, phiX, HD, 1, phi_x_b, nullptr, nullptr, 1, HD);
    // enc pre: [phiX | h] @ enc_w (K=512, A-split) -> Gs1 (ld 256)
    gemm(phiX, 2, 0, HD, h_prev, 0, HD, HD, 2*HD,
         enc_w, nullptr, nullptr, HD, Gs1, HD, 1, nullptr, nullptr, nullptr, 0, HD);
    agg_b(Gs1, HD, Tb1, HD, HD, t, enc_b, 1);              // enc_t = relu(agg + b)
    // enc mean/std: Tb1 @ [mean_w | std_w] (M=128, wblk=64) -> Gs1 (ld 128)
    gemm(Tb1, 2, 0, HD, nullptr, 0, 0, HD, HD,
         enc_mean_w, enc_std_w, nullptr, ZD, Gs1, 128, 1, nullptr, nullptr, nullptr, 0, 128);
    agg_f(Gs1, 128, ms, 128, 128, t);
    enc_post_k<<<(N*ZD)/256,256,0,stream>>>(ms, enc_mean_b, enc_std_b,
        eps, (size_t)t*N*ZD, zbuf, d_out, OUT_EM + (size_t)t*N*ZD, dflag);
    // prior: relu(h @ prior_w + b) -> Tb2; [mean|std] (M=128) -> pms (f32)
    gemm(h_prev, 0, 0, HD, nullptr, 0, 0, HD, HD,
         prior_w, nullptr, nullptr, HD, Tb2, HD, 1, prior_b, nullptr, nullptr, 1, HD);
    gemm(Tb2, 2, 0, HD, nullptr, 0, 0, HD, HD,
         prior_mean_w, prior_std_w, nullptr, ZD, pms, 128, 0,
         prior_mean_b, prior_std_b, nullptr, 0, 128);
    prior_post_kld_k<<<(N*ZD)/256,256,0,stream>>>(pms, ms, d_out,
        OUT_PM + (size_t)t*N*ZD, scal + 4, dflag);
    // phi_z = relu(z @ phi_z_w + b) -> Tb2 (prior_t dead)
    gemm(zbuf, 0, 0, ZD, nullptr, 0, 0, ZD, ZD,
         phi_z_w, nullptr, nullptr, HD, Tb2, HD, 1, phi_z_b, nullptr, nullptr, 1, HD);
    // decode + NLL
    dec_nll_k<<<dim3(64,64),256,0,stream>>>(zbuf, adj, (size_t)t*N*N, scal + t, scal + 5, dflag);
    // GRU x-side: [phiX|phiZ] @ {xz|xr|xh} fused (K=512, M=768) -> Gs1 (ld 768)
    gemm(phiX, 2, 0, HD, Tb2, 2, HD, HD, 2*HD,
         gru_xz_w, gru_xr_w, gru_xh_w, HD, Gs1, 768, 1, nullptr, nullptr, nullptr, 0, 768);
    // GRU h-side: h @ {hz|hr} fused (M=512) -> Gs2 (ld 512)
    gemm(h_prev, 0, 0, HD, nullptr, 0, 0, HD, HD,
         gru_hz_w, gru_hr_w, nullptr, HD, Gs2, 512, 1, nullptr, nullptr, nullptr, 0, 512);
    // gates
    agg2(t, Gs1, 768, Gs2, 512, nullptr, z_g, nullptr, 0, 0);            // z
    agg2(t, Gs1 + 256, 768, Gs2 + 256, 512, nullptr, Tb1, nullptr, 0, 1);// rh -> Tb1
    // candidate: rh @ hh_w -> Gs2 (ld 256); update h
    gemm(Tb1, 2, 0, HD, nullptr, 0, 0, HD, HD,
         gru_hh_w, nullptr, nullptr, HD, Gs2, HD, 1, nullptr, nullptr, nullptr, 0, HD);
    agg2(t, Gs1 + 512, 768, Gs2, 256, z_g, nullptr,
         (t == T_STEPS-1) ? d_out : (void*)nullptr, OUT_H, 2);
  }
  finalize_k<<<1,64,0,stream>>>(scal, d_out, dflag);
}

// Round 5
// 1797.138 us; speedup vs baseline: 2.9175x; 1.7277x over previous
//
#include <hip/hip_runtime.h>
#include <hip/hip_bf16.h>

#define T_STEPS 4
#define N 4096
#define E 65536
#define XD 256
#define HD 256
#define ZD 64

typedef __hip_bfloat16 bf16;
typedef __attribute__((ext_vector_type(8))) short short8;
typedef __attribute__((ext_vector_type(4))) float f32x4;

__device__ __forceinline__ float b2f(bf16 v){ return __bfloat162float(v); }
__device__ __forceinline__ bf16 f2b(float v){ return __float2bfloat16(v); }
__device__ __forceinline__ short f2s(float v){ return __builtin_bit_cast(short, f2b(v)); }
__device__ __forceinline__ float bits2f(unsigned int s){ return __builtin_bit_cast(float, s << 16); }
__device__ __forceinline__ float splus(float x){ return (x > 20.f) ? x : log1pf(expf(x)); }
__device__ __forceinline__ float sigm(float x){ return 1.f/(1.f + expf(-x)); }

// dispatched input load / output store: f==1 -> float32 data, f==0 -> bf16 data
__device__ __forceinline__ float ldI(const void* p, size_t i, int f){
  return f ? ((const float*)p)[i] : b2f(((const bf16*)p)[i]);
}
__device__ __forceinline__ void stO(void* p, size_t i, float v, int f){
  if (f) ((float*)p)[i] = v; else ((bf16*)p)[i] = f2b(v);
}

// 8 consecutive bf16 -> 8 floats (16B load)
__device__ __forceinline__ void ld8b(const bf16* p, float v[8]){
  uint4 u = *(const uint4*)p;
  v[0]=bits2f(u.x & 0xffffu); v[1]=bits2f(u.x >> 16);
  v[2]=bits2f(u.y & 0xffffu); v[3]=bits2f(u.y >> 16);
  v[4]=bits2f(u.z & 0xffffu); v[5]=bits2f(u.z >> 16);
  v[6]=bits2f(u.w & 0xffffu); v[7]=bits2f(u.w >> 16);
}
__device__ __forceinline__ unsigned int pack2(float a, float b){
  return (unsigned int)(unsigned short)__builtin_bit_cast(unsigned short, f2b(a))
       | ((unsigned int)(unsigned short)__builtin_bit_cast(unsigned short, f2b(b)) << 16);
}

// ---------------- dtype probe ----------------
__global__ void detect_k(const void* __restrict__ x, int* __restrict__ dfp){
  if (threadIdx.x == 0){
    const unsigned short* u = (const unsigned short*)x;
    int big = 0;
    for (int i = 0; i < 256; i++){
      int e = (u[i] >> 7) & 0xFF;
      if (e >= 134) big++;
    }
    *dfp = (big > 16) ? 1 : 0;
  }
}

// ---------------- setup kernels ----------------
__global__ void zero_f32_k(float* p){ p[threadIdx.x] = 0.f; }

__global__ __launch_bounds__(256) void zero_i32_k(int* p, int n){
  int i = blockIdx.x*256 + threadIdx.x; if (i < n) p[i] = 0;
}

__global__ __launch_bounds__(256) void ld_copy2_k(const void* __restrict__ a, float* __restrict__ b,
                                                  bf16* __restrict__ c, int n, const int* __restrict__ dfp){
  int f = *dfp;
  int i = blockIdx.x*256 + threadIdx.x;
  if (i < n){ float v = ldI(a, i, f); b[i] = v; c[i] = f2b(v); }
}

__global__ __launch_bounds__(256) void count_deg_k(const int* __restrict__ ei, int* __restrict__ deg){
  int idx = blockIdx.x*256 + threadIdx.x;     // T*E total
  int t = idx >> 16, e = idx & (E-1);
  int dst = ei[(size_t)t*2*E + E + e] & (N-1);
  atomicAdd(&deg[t*N + dst], 1);
}

__global__ __launch_bounds__(256) void scan_k(const int* __restrict__ deg, int* __restrict__ offs,
                                              float* __restrict__ dinv){
  int t = blockIdx.x, tid = threadIdx.x;
  const int* dg = deg + t*N;
  int* of = offs + t*(N+1);
  __shared__ int sh[256];
  int base = tid*16;
  int loc[16]; int s = 0;
  #pragma unroll
  for (int i = 0; i < 16; i++){ loc[i] = s; s += dg[base+i]; }
  sh[tid] = s;
  __syncthreads();
  for (int o = 1; o < 256; o <<= 1){
    int v = (tid >= o) ? sh[tid-o] : 0;
    __syncthreads();
    sh[tid] += v;
    __syncthreads();
  }
  int pre = (tid == 0) ? 0 : sh[tid-1];
  #pragma unroll
  for (int i = 0; i < 16; i++) of[base+i] = pre + loc[i];
  if (tid == 255) of[N] = sh[255];
  #pragma unroll
  for (int i = 0; i < 16; i++) dinv[t*N + base + i] = rsqrtf(1.f + (float)dg[base+i]);
}

__global__ __launch_bounds__(256) void init_cursor_k(int* __restrict__ cur, const int* __restrict__ offs){
  int idx = blockIdx.x*256 + threadIdx.x;     // T*N
  int t = idx >> 12, n = idx & (N-1);
  cur[idx] = offs[t*(N+1) + n];
}

__global__ __launch_bounds__(256) void scatter_k(const int* __restrict__ ei, int* __restrict__ cur,
        int* __restrict__ srcs, float* __restrict__ enorm, const float* __restrict__ dinv){
  int idx = blockIdx.x*256 + threadIdx.x;     // T*E
  int t = idx >> 16, e = idx & (E-1);
  int s = ei[(size_t)t*2*E + e] & (N-1);
  int d = ei[(size_t)t*2*E + E + e] & (N-1);
  int p = atomicAdd(&cur[t*N + d], 1);
  if (p >= 0 && p < E){
    srcs[(size_t)t*E + p] = s;
    enorm[(size_t)t*E + p] = dinv[t*N + s] * dinv[t*N + d];
  }
}

__global__ __launch_bounds__(256) void adj_sum_k(const void* __restrict__ adj, float* __restrict__ scal,
                                                 const int* __restrict__ dfp){
  int f = *dfp;
  int t = blockIdx.y, tid = threadIdx.x;
  size_t base = (size_t)t*N*N;
  float s = 0.f;
  for (size_t i = (size_t)blockIdx.x*256 + tid; i < (size_t)N*N/8; i += 131072){
    if (f){
      const float* p = (const float*)adj + base + i*8;
      float4 a = *(const float4*)p, b = *(const float4*)(p+4);
      s += a.x+a.y+a.z+a.w + b.x+b.y+b.z+b.w;
    } else {
      float v[8]; ld8b((const bf16*)adj + base + i*8, v);
      #pragma unroll
      for (int j = 0; j < 8; j++) s += v[j];
    }
  }
  __shared__ float red[256];
  red[tid] = s; __syncthreads();
  for (int o = 128; o > 0; o >>= 1){ if (tid < o) red[tid] += red[tid+o]; __syncthreads(); }
  if (tid == 0) atomicAdd(&scal[t], red[0]);
}

// ---------------- MFMA GEMM ----------------
// C[rows x M] = [A1 (k<K1) | A2 (k>=K1)] @ W_sel(col) + bias_sel, opt relu.
// col block c0 picks W{0,1,2} by c0/wblk; W is [K x wblk] row-major.
// amode: 0 = f32 ws, 1 = input (dflag dispatch), 2 = bf16 ws. cmode: 0 = f32 C, 1 = bf16 C.
// block: 256 thr = 4 waves; 64x64 C tile; K chunked by 32.
__global__ __launch_bounds__(256) void gemm_k(
    const void* __restrict__ A1, int am1, size_t ao1, int lda1,
    const void* __restrict__ A2, int am2, size_t ao2, int lda2,
    int K1, int K,
    const void* __restrict__ W0, const void* __restrict__ W1, const void* __restrict__ W2,
    int wblk, void* __restrict__ C, int ldc, int cmode,
    const void* __restrict__ b0, const void* __restrict__ b1, const void* __restrict__ b2,
    int act, const int* __restrict__ dfp){
  int f = *dfp;
  __shared__ __align__(16) short As[64*40];   // [r][k], pad 40 (80B rows, 16B-aligned)
  __shared__ __align__(16) short Wt[64*40];   // [n][k] transposed
  int tid = threadIdx.x;
  int row0 = blockIdx.y*64, col0 = blockIdx.x*64;
  int widx = col0 / wblk, wcol = col0 % wblk;
  const void* W  = (widx == 0) ? W0 : ((widx == 1) ? W1 : W2);
  const void* bs = (widx == 0) ? b0 : ((widx == 1) ? b1 : b2);
  int ar = tid >> 2, akk = (tid & 3)*8;        // A staging: row, k-offset
  int wk = tid >> 3, wn = (tid & 7)*8;         // W staging: k-row, n-offset
  int wave = tid >> 6, lane = tid & 63, m = lane & 15, kq = lane >> 4;
  f32x4 acc[4] = {};
  for (int k0 = 0; k0 < K; k0 += 32){
    const void* A; int am; size_t ao; int lda; int kb;
    if (k0 < K1){ A = A1; am = am1; ao = ao1; lda = lda1; kb = k0; }
    else        { A = A2; am = am2; ao = ao2; lda = lda2; kb = k0 - K1; }
    // stage A chunk [64r x 32k] as bf16
    size_t aidx = ao + (size_t)(row0 + ar)*lda + kb + akk;
    short8 av;
    if (am == 2 || (am == 1 && f == 0)){
      av = *(const short8*)((const short*)A + aidx);
    } else {
      const float* Af = (const float*)A;
      float4 u0 = *(const float4*)(Af + aidx);
      float4 u1 = *(const float4*)(Af + aidx + 4);
      av[0]=f2s(u0.x); av[1]=f2s(u0.y); av[2]=f2s(u0.z); av[3]=f2s(u0.w);
      av[4]=f2s(u1.x); av[5]=f2s(u1.y); av[6]=f2s(u1.z); av[7]=f2s(u1.w);
    }
    *(short8*)&As[ar*40 + akk] = av;
    // stage W chunk [32k x 64n] transposed -> Wt[n][k]
    size_t wi = (size_t)(k0 + wk)*wblk + wcol + wn;
    short wv[8];
    if (f == 0){
      short8 t8 = *(const short8*)((const short*)W + wi);
      #pragma unroll
      for (int j = 0; j < 8; j++) wv[j] = t8[j];
    } else {
      const float* Wf = (const float*)W;
      float4 u0 = *(const float4*)(Wf + wi);
      float4 u1 = *(const float4*)(Wf + wi + 4);
      wv[0]=f2s(u0.x); wv[1]=f2s(u0.y); wv[2]=f2s(u0.z); wv[3]=f2s(u0.w);
      wv[4]=f2s(u1.x); wv[5]=f2s(u1.y); wv[6]=f2s(u1.z); wv[7]=f2s(u1.w);
    }
    #pragma unroll
    for (int j = 0; j < 8; j++) Wt[(wn + j)*40 + wk] = wv[j];
    __syncthreads();
    // compute: wave handles m-tile 'wave', 4 n-tiles
    short8 afr = *(const short8*)&As[(wave*16 + m)*40 + kq*8];
    #pragma unroll
    for (int t = 0; t < 4; t++){
      short8 bfr = *(const short8*)&Wt[(t*16 + m)*40 + kq*8];
      acc[t] = __builtin_amdgcn_mfma_f32_16x16x32_bf16(afr, bfr, acc[t], 0, 0, 0);
    }
    __syncthreads();
  }
  // epilogue: D[row=(lane>>4)*4+reg][col=lane&15] per tile
  #pragma unroll
  for (int t = 0; t < 4; t++){
    int c = col0 + t*16 + m;
    float bv = bs ? ldI(bs, wcol + t*16 + m, f) : 0.f;
    #pragma unroll
    for (int reg = 0; reg < 4; reg++){
      int r = row0 + wave*16 + kq*4 + reg;
      float v = acc[t][reg] + bv;
      if (act == 1) v = fmaxf(v, 0.f);
      size_t off = (size_t)r*ldc + c;
      if (cmode) ((bf16*)C)[off] = f2b(v); else ((float*)C)[off] = v;
    }
  }
}

// ---------------- GCN aggregation: NPB nodes/block, 8 cols/thread ----------------
// out[n,c] = act( dinv[n]^2*G[n,c] + sum_e norm_e*G[src_e,c] + bias[c] )
template<int NPB, int LPN, typename TO>
__global__ __launch_bounds__(256) void gcn_agg_k(const bf16* __restrict__ G, int ld,
    TO* __restrict__ outp, int ldo,
    const int* __restrict__ offs, const int* __restrict__ srcs,
    const float* __restrict__ enorm, const float* __restrict__ dinv,
    const void* __restrict__ bias, int act, const int* __restrict__ dfp){
  int f = *dfp;
  int g = threadIdx.x / LPN, l = threadIdx.x % LPN;
  int n = blockIdx.x*NPB + g;
  int c = l*8;
  int e0 = offs[n], e1 = offs[n+1];
  float d2 = dinv[n]*dinv[n];
  float acc[8], v[8];
  ld8b(G + (size_t)n*ld + c, v);
  #pragma unroll
  for (int j = 0; j < 8; j++) acc[j] = d2 * v[j];
  for (int e = e0; e < e1; e++){
    int s = srcs[e] & (N-1);
    float nm = enorm[e];
    ld8b(G + (size_t)s*ld + c, v);
    #pragma unroll
    for (int j = 0; j < 8; j++) acc[j] += nm * v[j];
  }
  #pragma unroll
  for (int j = 0; j < 8; j++){
    if (bias) acc[j] += ldI(bias, c + j, f);
    if (act == 1) acc[j] = fmaxf(acc[j], 0.f);
  }
  size_t base = (size_t)n*ldo + c;
  if constexpr (sizeof(TO) == 2){
    uint4 o; o.x = pack2(acc[0],acc[1]); o.y = pack2(acc[2],acc[3]);
    o.z = pack2(acc[4],acc[5]); o.w = pack2(acc[6],acc[7]);
    *(uint4*)((bf16*)outp + base) = o;
  } else {
    float4 o0 = {acc[0],acc[1],acc[2],acc[3]}, o1 = {acc[4],acc[5],acc[6],acc[7]};
    *(float4*)((float*)outp + base) = o0;
    *(float4*)((float*)outp + base + 4) = o1;
  }
}

// ---------------- fused dual-GCN aggregation for GRU gates (M=256: 8 nodes, 32 lanes) ----
// mode 0: z = sig(agg(G1)+agg(G2))                  -> (float*)outv
// mode 1: rh = sig(agg(G1)+agg(G2)) * hbuf          -> (bf16*)outv
// mode 2: h' = z*hbuf + (1-z)*tanh(agg(G1)+agg(G2)) -> hbuf + hbf (+opt outg at ooff)
__global__ __launch_bounds__(256) void gcn_agg2_k(
    const bf16* __restrict__ G1, int ld1, const bf16* __restrict__ G2, int ld2,
    const int* __restrict__ offs, const int* __restrict__ srcs,
    const float* __restrict__ enorm, const float* __restrict__ dinv,
    const float* __restrict__ zgate, float* __restrict__ hbuf, bf16* __restrict__ hbf,
    void* __restrict__ outv, void* __restrict__ outg, size_t ooff,
    int mode, const int* __restrict__ dfp){
  int f = *dfp;
  int g = threadIdx.x >> 5, l = threadIdx.x & 31;
  int n = blockIdx.x*8 + g;
  int c = l*8;
  int e0 = offs[n], e1 = offs[n+1];
  float d2 = dinv[n]*dinv[n];
  float a1[8], a2[8], v[8];
  ld8b(G1 + (size_t)n*ld1 + c, v);
  #pragma unroll
  for (int j = 0; j < 8; j++) a1[j] = d2 * v[j];
  ld8b(G2 + (size_t)n*ld2 + c, v);
  #pragma unroll
  for (int j = 0; j < 8; j++) a2[j] = d2 * v[j];
  for (int e = e0; e < e1; e++){
    int s = srcs[e] & (N-1);
    float nm = enorm[e];
    ld8b(G1 + (size_t)s*ld1 + c, v);
    #pragma unroll
    for (int j = 0; j < 8; j++) a1[j] += nm * v[j];
    ld8b(G2 + (size_t)s*ld2 + c, v);
    #pragma unroll
    for (int j = 0; j < 8; j++) a2[j] += nm * v[j];
  }
  size_t base = (size_t)n*HD + c;
  if (mode == 0){
    float4 o0, o1;
    o0.x = sigm(a1[0]+a2[0]); o0.y = sigm(a1[1]+a2[1]);
    o0.z = sigm(a1[2]+a2[2]); o0.w = sigm(a1[3]+a2[3]);
    o1.x = sigm(a1[4]+a2[4]); o1.y = sigm(a1[5]+a2[5]);
    o1.z = sigm(a1[6]+a2[6]); o1.w = sigm(a1[7]+a2[7]);
    *(float4*)((float*)outv + base) = o0;
    *(float4*)((float*)outv + base + 4) = o1;
  } else if (mode == 1){
    float r[8];
    #pragma unroll
    for (int j = 0; j < 8; j++) r[j] = sigm(a1[j]+a2[j]) * hbuf[base+j];
    uint4 o; o.x = pack2(r[0],r[1]); o.y = pack2(r[2],r[3]);
    o.z = pack2(r[4],r[5]); o.w = pack2(r[6],r[7]);
    *(uint4*)((bf16*)outv + base) = o;
  } else {
    #pragma unroll
    for (int j = 0; j < 8; j++){
      float z = zgate[base+j];
      float hv = hbuf[base+j];
      float nv = z*hv + (1.f - z)*tanhf(a1[j]+a2[j]);
      hbuf[base+j] = nv;
      hbf[base+j] = f2b(nv);
      if (outg) stO(outg, ooff + base + j, nv, f);
    }
  }
}

// ---------------- per-step small kernels ----------------
__global__ __launch_bounds__(256) void enc_post_k(float* __restrict__ ms, const void* __restrict__ mb,
    const void* __restrict__ sb, const void* __restrict__ eps, size_t eoff,
    float* __restrict__ z, void* __restrict__ outg, size_t ooff, const int* __restrict__ dfp){
  int f = *dfp;
  int idx = blockIdx.x*256 + threadIdx.x;   // N*ZD
  int n = idx >> 6, d = idx & 63;
  float mean = ms[n*128 + d] + ldI(mb, d, f);
  float sd = splus(ms[n*128 + 64 + d] + ldI(sb, d, f));
  ms[n*128 + d] = mean;
  ms[n*128 + 64 + d] = sd;
  z[idx] = ldI(eps, eoff + idx, f) * sd + mean;
  stO(outg, ooff + idx, mean, f);
}

__global__ __launch_bounds__(256) void prior_post_kld_k(const float* __restrict__ pms,
    const float* __restrict__ ms, void* __restrict__ outg, size_t ooff,
    float* __restrict__ kacc, const int* __restrict__ dfp){
  int f = *dfp;
  int idx = blockIdx.x*256 + threadIdx.x;   // N*ZD
  int tid = threadIdx.x;
  int n = idx >> 6, d = idx & 63;
  float pm = pms[n*128 + d];
  float ps = splus(pms[n*128 + 64 + d]);
  float em = ms[n*128 + d];
  float es = ms[n*128 + 64 + d];
  float s1 = es + 1e-10f, s2 = ps + 1e-10f;
  float dm = em - pm;
  float el = 2.f*(logf(s2) - logf(s1)) - (s1*s1 + dm*dm)/(s2*s2) + 1.f;
  stO(outg, ooff + idx, pm, f);
  __shared__ float red[256];
  red[tid] = el; __syncthreads();
  for (int o = 128; o > 0; o >>= 1){ if (tid < o) red[tid] += red[tid+o]; __syncthreads(); }
  if (tid == 0) atomicAdd(kacc, red[0] * (0.5f/((float)N*(float)ZD)));
}

// ---------------- decode + NLL ----------------
__global__ __launch_bounds__(256, 3) void dec_nll_k(const float* __restrict__ z,
    const void* __restrict__ a, size_t aoff, const float* __restrict__ tsum,
    float* __restrict__ nll_acc, const int* __restrict__ dfp){
  int f = *dfp;
  __shared__ float ziT[64*68];   // [d][row], stride 68 -> 16B-aligned float4 rows
  __shared__ float zjT[64*68];
  int tid = threadIdx.x;
  int i0 = blockIdx.y*64, j0 = blockIdx.x*64;
  #pragma unroll
  for (int k = 0; k < 16; k++){
    int ii = tid + k*256; int r = ii >> 6, d = ii & 63;
    ziT[d*68 + r] = z[(size_t)(i0+r)*ZD + d];
    zjT[d*68 + r] = z[(size_t)(j0+r)*ZD + d];
  }
  __syncthreads();
  int tx = tid & 15, ty = tid >> 4;
  float acc[4][4] = {};
  #pragma unroll 8
  for (int d = 0; d < 64; d++){
    float4 ra = *(const float4*)&ziT[d*68 + ty*4];
    float4 rb = *(const float4*)&zjT[d*68 + tx*4];
    acc[0][0] += ra.x*rb.x; acc[0][1] += ra.x*rb.y; acc[0][2] += ra.x*rb.z; acc[0][3] += ra.x*rb.w;
    acc[1][0] += ra.y*rb.x; acc[1][1] += ra.y*rb.y; acc[1][2] += ra.y*rb.z; acc[1][3] += ra.y*rb.w;
    acc[2][0] += ra.z*rb.x; acc[2][1] += ra.z*rb.y; acc[2][2] += ra.z*rb.z; acc[2][3] += ra.z*rb.w;
    acc[3][0] += ra.w*rb.x; acc[3][1] += ra.w*rb.y; acc[3][2] += ra.w*rb.z; acc[3][3] += ra.w*rb.w;
  }
  float ts = *tsum;
  const float NNf = 16777216.f;
  float posw = (NNf - ts)/ts;
  float local = 0.f;
  #pragma unroll
  for (int p = 0; p < 4; p++){
    int i = i0 + ty*4 + p;
    size_t rowoff = aoff + (size_t)i*N + j0 + tx*4;
    float av4[4];
    if (f){
      float4 v = *(const float4*)((const float*)a + rowoff);
      av4[0] = v.x; av4[1] = v.y; av4[2] = v.z; av4[3] = v.w;
    } else {
      const bf16* pb = (const bf16*)a + rowoff;
      av4[0] = b2f(pb[0]); av4[1] = b2f(pb[1]); av4[2] = b2f(pb[2]); av4[3] = b2f(pb[3]);
    }
    #pragma unroll
    for (int q = 0; q < 4; q++){
      float dec = sigm(acc[p][q]);
      float av = av4[q];
      float bce = (1.f - av)*log1pf(expf(dec));
      if (av != 0.f) bce += posw*av*log1pf(expf(-dec));
      local += bce;
    }
  }
  __syncthreads();
  ziT[tid] = local; __syncthreads();
  for (int o = 128; o > 0; o >>= 1){ if (tid < o) ziT[tid] += ziT[tid+o]; __syncthreads(); }
  if (tid == 0) atomicAdd(nll_acc, ziT[0] * 0.5f/(NNf - ts));
}

__global__ void finalize_k(const float* __restrict__ scal, void* __restrict__ outg,
                           const int* __restrict__ dfp){
  int f = *dfp;
  if (threadIdx.x == 0) stO(outg, 0, scal[4], f);
  if (threadIdx.x == 1) stO(outg, 1, scal[5], f);
}

// ---------------- host ----------------
extern "C" void kernel_launch(void* const* d_in, const int* in_sizes, int n_in,
                              void* d_out, int out_size, void* d_ws, size_t ws_size,
                              hipStream_t stream){
  const void* x           = d_in[0];
  const int*  ei          = (const int*)d_in[1];
  const void* adj         = d_in[2];
  const void* eps         = d_in[3];
  const void* h0          = d_in[4];
  const void* phi_x_w     = d_in[5];
  const void* phi_x_b     = d_in[6];
  const void* phi_z_w     = d_in[7];
  const void* phi_z_b     = d_in[8];
  const void* enc_w       = d_in[9];
  const void* enc_b       = d_in[10];
  const void* enc_mean_w  = d_in[11];
  const void* enc_mean_b  = d_in[12];
  const void* enc_std_w   = d_in[13];
  const void* enc_std_b   = d_in[14];
  const void* prior_w     = d_in[15];
  const void* prior_b     = d_in[16];
  const void* prior_mean_w= d_in[17];
  const void* prior_mean_b= d_in[18];
  const void* prior_std_w = d_in[19];
  const void* prior_std_b = d_in[20];
  const void* gru_xz_w    = d_in[21];
  const void* gru_hz_w    = d_in[22];
  const void* gru_xr_w    = d_in[23];
  const void* gru_hr_w    = d_in[24];
  const void* gru_xh_w    = d_in[25];
  const void* gru_hh_w    = d_in[26];

  // bump allocator over d_ws (~45 MB total)
  char* wp = (char*)d_ws;
  auto alloc = [&](size_t bytes){ void* p = (void*)wp; wp += (bytes + 255) & ~(size_t)255; return p; };
  float* scal  = (float*)alloc(64*sizeof(float));          // [0..3]=tsum per t, [4]=kld, [5]=nll
  int*   dflag = (int*)  alloc(256);
  float* dinv  = (float*)alloc((size_t)T_STEPS*N*4);
  int*   offs  = (int*)  alloc((size_t)T_STEPS*(N+1)*4);
  int*   srcs  = (int*)  alloc((size_t)T_STEPS*E*4);
  float* enorm = (float*)alloc((size_t)T_STEPS*E*4);
  int*   deg   = (int*)  alloc((size_t)T_STEPS*N*4);       // reused as scatter cursor
  float* h_prev= (float*)alloc((size_t)N*HD*4);
  bf16*  h_bf  = (bf16*) alloc((size_t)N*HD*2);
  bf16*  phiXa = (bf16*) alloc((size_t)T_STEPS*N*HD*2);    // all steps
  bf16*  Tb1   = (bf16*) alloc((size_t)N*HD*2);            // enc_t, later rh
  bf16*  Tb2   = (bf16*) alloc((size_t)N*HD*2);            // prior_t, later phiZ
  float* zbuf  = (float*)alloc((size_t)N*ZD*4);
  float* ms    = (float*)alloc((size_t)N*128*4);           // enc [mean|std]
  float* pms   = (float*)alloc((size_t)N*128*4);           // prior [mean|stdpre]
  float* z_g   = (float*)alloc((size_t)N*HD*4);
  bf16*  Gs1   = (bf16*) alloc((size_t)N*768*2);           // GEMM staging wide
  bf16*  Gs2   = (bf16*) alloc((size_t)N*512*2);

  detect_k<<<1,64,0,stream>>>(x, dflag);
  zero_f32_k<<<1,64,0,stream>>>(scal);
  zero_i32_k<<<(T_STEPS*N)/256,256,0,stream>>>(deg, T_STEPS*N);
  count_deg_k<<<(T_STEPS*E)/256,256,0,stream>>>(ei, deg);
  scan_k<<<T_STEPS,256,0,stream>>>(deg, offs, dinv);
  init_cursor_k<<<(T_STEPS*N)/256,256,0,stream>>>(deg, offs);
  scatter_k<<<(T_STEPS*E)/256,256,0,stream>>>(ei, deg, srcs, enorm, dinv);
  adj_sum_k<<<dim3(512,T_STEPS),256,0,stream>>>(adj, scal, dflag);
  ld_copy2_k<<<(N*HD)/256,256,0,stream>>>(h0, h_prev, h_bf, N*HD, dflag);

  auto gemm = [&](const void* A1, int am1, size_t ao1, int lda1,
                  const void* A2, int am2, int lda2, int K1, int K,
                  const void* W0, const void* W1, const void* W2, int wblk,
                  void* C, int ldc, int cmode,
                  const void* b0, const void* b1, const void* b2, int act,
                  int M, int rows){
    dim3 g(M/64, rows/64);
    gemm_k<<<g,256,0,stream>>>(A1, am1, ao1, lda1, A2, am2, 0, lda2, K1, K,
                               W0, W1, W2, wblk, C, ldc, cmode, b0, b1, b2, act, dflag);
  };
  auto agg_b = [&](const bf16* G, int ld, bf16* o, int ldo, int t, const void* bias, int act){
    gcn_agg_k<8,32,bf16><<<N/8,256,0,stream>>>(G, ld, o, ldo, offs + t*(N+1),
        srcs + (size_t)t*E, enorm + (size_t)t*E, dinv + t*N, bias, act, dflag);
  };
  auto agg_f128 = [&](const bf16* G, int ld, float* o, int ldo, int t){
    gcn_agg_k<16,16,float><<<N/16,256,0,stream>>>(G, ld, o, ldo, offs + t*(N+1),
        srcs + (size_t)t*E, enorm + (size_t)t*E, dinv + t*N, nullptr, 0, dflag);
  };
  auto agg2 = [&](int t, const bf16* G1, int ld1, const bf16* G2, int ld2,
                  const float* zg, void* ov, void* og, size_t ooff, int mode){
    gcn_agg2_k<<<N/8,256,0,stream>>>(G1, ld1, G2, ld2, offs + t*(N+1), srcs + (size_t)t*E,
                                     enorm + (size_t)t*E, dinv + t*N, zg, h_prev, h_bf,
                                     ov, og, ooff, mode, dflag);
  };

  const size_t OUT_EM = 2;
  const size_t OUT_PM = 2 + (size_t)T_STEPS*N*ZD;
  const size_t OUT_H  = 2 + (size_t)2*T_STEPS*N*ZD;

  // phi_x for ALL steps: relu(x @ phi_x_w + b) -> phiXa  [T*N x 256]
  gemm(x, 1, 0, XD, nullptr, 0, 0, XD, XD,
       phi_x_w, nullptr, nullptr, HD, phiXa, HD, 1, phi_x_b, nullptr, nullptr, 1,
       HD, T_STEPS*N);

  for (int t = 0; t < T_STEPS; t++){
    const bf16* phiX = phiXa + (size_t)t*N*HD;
    // enc pre: [phiX | h] @ enc_w (K=512) -> Gs1 (ld 256)
    gemm(phiX, 2, 0, HD, h_bf, 2, HD, HD, 2*HD,
         enc_w, nullptr, nullptr, HD, Gs1, HD, 1, nullptr, nullptr, nullptr, 0, HD, N);
    agg_b(Gs1, HD, Tb1, HD, t, enc_b, 1);                  // enc_t = relu(agg + b)
    // enc mean/std: Tb1 @ [mean_w | std_w] (M=128, wblk=64) -> Gs1 (ld 128)
    gemm(Tb1, 2, 0, HD, nullptr, 0, 0, HD, HD,
         enc_mean_w, enc_std_w, nullptr, ZD, Gs1, 128, 1,
         nullptr, nullptr, nullptr, 0, 128, N);
    agg_f128(Gs1, 128, ms, 128, t);
    enc_post_k<<<(N*ZD)/256,256,0,stream>>>(ms, enc_mean_b, enc_std_b,
        eps, (size_t)t*N*ZD, zbuf, d_out, OUT_EM + (size_t)t*N*ZD, dflag);
    // prior: relu(h @ prior_w + b) -> Tb2; [mean|std] (M=128) -> pms (f32)
    gemm(h_bf, 2, 0, HD, nullptr, 0, 0, HD, HD,
         prior_w, nullptr, nullptr, HD, Tb2, HD, 1, prior_b, nullptr, nullptr, 1, HD, N);
    gemm(Tb2, 2, 0, HD, nullptr, 0, 0, HD, HD,
         prior_mean_w, prior_std_w, nullptr, ZD, pms, 128, 0,
         prior_mean_b, prior_std_b, nullptr, 0, 128, N);
    prior_post_kld_k<<<(N*ZD)/256,256,0,stream>>>(pms, ms, d_out,
        OUT_PM + (size_t)t*N*ZD, scal + 4, dflag);
    // phi_z = relu(z @ phi_z_w + b) -> Tb2 (prior_t dead)
    gemm(zbuf, 0, 0, ZD, nullptr, 0, 0, ZD, ZD,
         phi_z_w, nullptr, nullptr, HD, Tb2, HD, 1, phi_z_b, nullptr, nullptr, 1, HD, N);
    // decode + NLL
    dec_nll_k<<<dim3(64,64),256,0,stream>>>(zbuf, adj, (size_t)t*N*N, scal + t, scal + 5, dflag);
    // GRU x-side: [phiX|phiZ] @ {xz|xr|xh} fused (K=512, M=768) -> Gs1 (ld 768)
    gemm(phiX, 2, 0, HD, Tb2, 2, HD, HD, 2*HD,
         gru_xz_w, gru_xr_w, gru_xh_w, HD, Gs1, 768, 1,
         nullptr, nullptr, nullptr, 0, 768, N);
    // GRU h-side: h @ {hz|hr} fused (M=512) -> Gs2 (ld 512)
    gemm(h_bf, 2, 0, HD, nullptr, 0, 0, HD, HD,
         gru_hz_w, gru_hr_w, nullptr, HD, Gs2, 512, 1,
         nullptr, nullptr, nullptr, 0, 512, N);
    // gates
    agg2(t, Gs1, 768, Gs2, 512, nullptr, z_g, nullptr, 0, 0);            // z -> z_g
    agg2(t, Gs1 + 256, 768, Gs2 + 256, 512, nullptr, Tb1, nullptr, 0, 1);// rh -> Tb1
    // candidate: rh @ hh_w -> Gs2 (ld 256); update h
    gemm(Tb1, 2, 0, HD, nullptr, 0, 0, HD, HD,
         gru_hh_w, nullptr, nullptr, HD, Gs2, HD, 1,
         nullptr, nullptr, nullptr, 0, HD, N);
    agg2(t, Gs1 + 512, 768, Gs2, 256, z_g, nullptr,
         (t == T_STEPS-1) ? d_out : (void*)nullptr, OUT_H, 2);
  }
  finalize_k<<<1,64,0,stream>>>(scal, d_out, dflag);
}

// Round 6
// 1584.292 us; speedup vs baseline: 3.3095x; 1.1343x over previous
//
#include <hip/hip_runtime.h>
#include <hip/hip_bf16.h>

#define T_STEPS 4
#define N 4096
#define E 65536
#define XD 256
#define HD 256
#define ZD 64

typedef __hip_bfloat16 bf16;
typedef __attribute__((ext_vector_type(8))) short short8;
typedef __attribute__((ext_vector_type(4))) float f32x4;

__device__ __forceinline__ float b2f(bf16 v){ return __bfloat162float(v); }
__device__ __forceinline__ bf16 f2b(float v){ return __float2bfloat16(v); }
__device__ __forceinline__ short f2s(float v){ return __builtin_bit_cast(short, f2b(v)); }
__device__ __forceinline__ float bits2f(unsigned int s){ return __builtin_bit_cast(float, s << 16); }
__device__ __forceinline__ float splus(float x){ return (x > 20.f) ? x : log1pf(expf(x)); }
__device__ __forceinline__ float sigm(float x){ return 1.f/(1.f + expf(-x)); }

// dispatched input load / output store: f==1 -> float32 data, f==0 -> bf16 data
__device__ __forceinline__ float ldI(const void* p, size_t i, int f){
  return f ? ((const float*)p)[i] : b2f(((const bf16*)p)[i]);
}
__device__ __forceinline__ void stO(void* p, size_t i, float v, int f){
  if (f) ((float*)p)[i] = v; else ((bf16*)p)[i] = f2b(v);
}

// 8 consecutive bf16 -> 8 floats (16B load)
__device__ __forceinline__ void ld8b(const bf16* p, float v[8]){
  uint4 u = *(const uint4*)p;
  v[0]=bits2f(u.x & 0xffffu); v[1]=bits2f(u.x >> 16);
  v[2]=bits2f(u.y & 0xffffu); v[3]=bits2f(u.y >> 16);
  v[4]=bits2f(u.z & 0xffffu); v[5]=bits2f(u.z >> 16);
  v[6]=bits2f(u.w & 0xffffu); v[7]=bits2f(u.w >> 16);
}
__device__ __forceinline__ unsigned int pack2(float a, float b){
  return (unsigned int)(unsigned short)__builtin_bit_cast(unsigned short, f2b(a))
       | ((unsigned int)(unsigned short)__builtin_bit_cast(unsigned short, f2b(b)) << 16);
}

// ---------------- dtype probe ----------------
__global__ void detect_k(const void* __restrict__ x, int* __restrict__ dfp){
  if (threadIdx.x == 0){
    const unsigned short* u = (const unsigned short*)x;
    int big = 0;
    for (int i = 0; i < 256; i++){
      int e = (u[i] >> 7) & 0xFF;
      if (e >= 134) big++;
    }
    *dfp = (big > 16) ? 1 : 0;
  }
}

// ---------------- setup kernels ----------------
__global__ void zero_f32_k(float* p){ p[threadIdx.x] = 0.f; }

__global__ __launch_bounds__(256) void zero_i32_k(int* p, int n){
  int i = blockIdx.x*256 + threadIdx.x; if (i < n) p[i] = 0;
}

__global__ __launch_bounds__(256) void ld_copy2_k(const void* __restrict__ a, float* __restrict__ b,
                                                  bf16* __restrict__ c, int n, const int* __restrict__ dfp){
  int f = *dfp;
  int i = blockIdx.x*256 + threadIdx.x;
  if (i < n){ float v = ldI(a, i, f); b[i] = v; c[i] = f2b(v); }
}

__global__ __launch_bounds__(256) void count_deg_k(const int* __restrict__ ei, int* __restrict__ deg){
  int idx = blockIdx.x*256 + threadIdx.x;     // T*E total
  int t = idx >> 16, e = idx & (E-1);
  int dst = ei[(size_t)t*2*E + E + e] & (N-1);
  atomicAdd(&deg[t*N + dst], 1);
}

__global__ __launch_bounds__(256) void scan_k(const int* __restrict__ deg, int* __restrict__ offs,
                                              float* __restrict__ dinv){
  int t = blockIdx.x, tid = threadIdx.x;
  const int* dg = deg + t*N;
  int* of = offs + t*(N+1);
  __shared__ int sh[256];
  int base = tid*16;
  int loc[16]; int s = 0;
  #pragma unroll
  for (int i = 0; i < 16; i++){ loc[i] = s; s += dg[base+i]; }
  sh[tid] = s;
  __syncthreads();
  for (int o = 1; o < 256; o <<= 1){
    int v = (tid >= o) ? sh[tid-o] : 0;
    __syncthreads();
    sh[tid] += v;
    __syncthreads();
  }
  int pre = (tid == 0) ? 0 : sh[tid-1];
  #pragma unroll
  for (int i = 0; i < 16; i++) of[base+i] = pre + loc[i];
  if (tid == 255) of[N] = sh[255];
  #pragma unroll
  for (int i = 0; i < 16; i++) dinv[t*N + base + i] = rsqrtf(1.f + (float)dg[base+i]);
}

__global__ __launch_bounds__(256) void init_cursor_k(int* __restrict__ cur, const int* __restrict__ offs){
  int idx = blockIdx.x*256 + threadIdx.x;     // T*N
  int t = idx >> 12, n = idx & (N-1);
  cur[idx] = offs[t*(N+1) + n];
}

__global__ __launch_bounds__(256) void scatter_k(const int* __restrict__ ei, int* __restrict__ cur,
        int* __restrict__ srcs, float* __restrict__ enorm, const float* __restrict__ dinv){
  int idx = blockIdx.x*256 + threadIdx.x;     // T*E
  int t = idx >> 16, e = idx & (E-1);
  int s = ei[(size_t)t*2*E + e] & (N-1);
  int d = ei[(size_t)t*2*E + E + e] & (N-1);
  int p = atomicAdd(&cur[t*N + d], 1);
  if (p >= 0 && p < E){
    srcs[(size_t)t*E + p] = s;
    enorm[(size_t)t*E + p] = dinv[t*N + s] * dinv[t*N + d];
  }
}

// ---------------- MFMA GEMM (single/dual-A, up to 3 W; legacy path for inputs) --------------
// C[rows x M]; amode: 0 = f32 ws, 1 = input (dflag dispatch), 2 = bf16 ws. cmode: 0=f32, 1=bf16.
__global__ __launch_bounds__(256) void gemm_k(
    const void* __restrict__ A1, int am1, size_t ao1, int lda1,
    const void* __restrict__ A2, int am2, size_t ao2, int lda2,
    int K1, int K,
    const void* __restrict__ W0, const void* __restrict__ W1, const void* __restrict__ W2,
    int wblk, void* __restrict__ C, int ldc, int cmode,
    const void* __restrict__ b0, const void* __restrict__ b1, const void* __restrict__ b2,
    int act, const int* __restrict__ dfp){
  int f = *dfp;
  __shared__ __align__(16) short As[64*40];
  __shared__ __align__(16) short Wt[64*40];
  int tid = threadIdx.x;
  int row0 = blockIdx.y*64, col0 = blockIdx.x*64;
  int widx = col0 / wblk, wcol = col0 % wblk;
  const void* W  = (widx == 0) ? W0 : ((widx == 1) ? W1 : W2);
  const void* bs = (widx == 0) ? b0 : ((widx == 1) ? b1 : b2);
  int ar = tid >> 2, akk = (tid & 3)*8;
  int wk = tid >> 3, wn = (tid & 7)*8;
  int wave = tid >> 6, lane = tid & 63, m = lane & 15, kq = lane >> 4;
  f32x4 acc[4] = {};
  for (int k0 = 0; k0 < K; k0 += 32){
    const void* A; int am; size_t ao; int lda; int kb;
    if (k0 < K1){ A = A1; am = am1; ao = ao1; lda = lda1; kb = k0; }
    else        { A = A2; am = am2; ao = ao2; lda = lda2; kb = k0 - K1; }
    size_t aidx = ao + (size_t)(row0 + ar)*lda + kb + akk;
    short8 av;
    if (am == 2 || (am == 1 && f == 0)){
      av = *(const short8*)((const short*)A + aidx);
    } else {
      const float* Af = (const float*)A;
      float4 u0 = *(const float4*)(Af + aidx);
      float4 u1 = *(const float4*)(Af + aidx + 4);
      av[0]=f2s(u0.x); av[1]=f2s(u0.y); av[2]=f2s(u0.z); av[3]=f2s(u0.w);
      av[4]=f2s(u1.x); av[5]=f2s(u1.y); av[6]=f2s(u1.z); av[7]=f2s(u1.w);
    }
    *(short8*)&As[ar*40 + akk] = av;
    size_t wi = (size_t)(k0 + wk)*wblk + wcol + wn;
    short wv[8];
    if (f == 0){
      short8 t8 = *(const short8*)((const short*)W + wi);
      #pragma unroll
      for (int j = 0; j < 8; j++) wv[j] = t8[j];
    } else {
      const float* Wf = (const float*)W;
      float4 u0 = *(const float4*)(Wf + wi);
      float4 u1 = *(const float4*)(Wf + wi + 4);
      wv[0]=f2s(u0.x); wv[1]=f2s(u0.y); wv[2]=f2s(u0.z); wv[3]=f2s(u0.w);
      wv[4]=f2s(u1.x); wv[5]=f2s(u1.y); wv[6]=f2s(u1.z); wv[7]=f2s(u1.w);
    }
    #pragma unroll
    for (int j = 0; j < 8; j++) Wt[(wn + j)*40 + wk] = wv[j];
    __syncthreads();
    short8 afr = *(const short8*)&As[(wave*16 + m)*40 + kq*8];
    #pragma unroll
    for (int t = 0; t < 4; t++){
      short8 bfr = *(const short8*)&Wt[(t*16 + m)*40 + kq*8];
      acc[t] = __builtin_amdgcn_mfma_f32_16x16x32_bf16(afr, bfr, acc[t], 0, 0, 0);
    }
    __syncthreads();
  }
  #pragma unroll
  for (int t = 0; t < 4; t++){
    int c = col0 + t*16 + m;
    float bv = bs ? ldI(bs, wcol + t*16 + m, f) : 0.f;
    #pragma unroll
    for (int reg = 0; reg < 4; reg++){
      int r = row0 + wave*16 + kq*4 + reg;
      float v = acc[t][reg] + bv;
      if (act == 1) v = fmaxf(v, 0.f);
      size_t off = (size_t)r*ldc + c;
      if (cmode) ((bf16*)C)[off] = f2b(v); else ((float*)C)[off] = v;
    }
  }
}

// ---------------- descriptor multi-GEMM (bf16 ws A, bf16 C) ----------------
struct GD {
  const bf16* A1; const bf16* A2;   // A1 for global k<256, A2 for k>=256
  int lda1, lda2;
  const void* W; int ldw; int wcol; // W [krange x ldw] input-dtype; wcol = 64-block offset in W
  const void* bias;                 // input-dtype, indexed by wcol+...
  int kbeg, kend, act;
};
struct GDs { GD d[16]; };

__global__ __launch_bounds__(256) void gemm_multi_k(GDs descs, bf16* __restrict__ C, int ldc,
                                                    const int* __restrict__ dfp){
  int f = *dfp;
  __shared__ __align__(16) short As[64*40];
  __shared__ __align__(16) short Wt[64*40];
  GD g = descs.d[blockIdx.x];
  int tid = threadIdx.x;
  int row0 = blockIdx.y*64, col0 = blockIdx.x*64;
  int ar = tid >> 2, akk = (tid & 3)*8;
  int wk = tid >> 3, wn = (tid & 7)*8;
  int wave = tid >> 6, lane = tid & 63, m = lane & 15, kq = lane >> 4;
  f32x4 acc[4] = {};
  for (int k0 = g.kbeg; k0 < g.kend; k0 += 32){
    const bf16* A; int lda, kb;
    if (k0 < 256){ A = g.A1; lda = g.lda1; kb = k0; }
    else         { A = g.A2; lda = g.lda2; kb = k0 - 256; }
    *(short8*)&As[ar*40 + akk] =
        *(const short8*)((const short*)A + (size_t)(row0 + ar)*lda + kb + akk);
    size_t wi = (size_t)(k0 - g.kbeg + wk)*g.ldw + g.wcol + wn;
    short wv[8];
    if (f == 0){
      short8 t8 = *(const short8*)((const short*)g.W + wi);
      #pragma unroll
      for (int j = 0; j < 8; j++) wv[j] = t8[j];
    } else {
      const float* Wf = (const float*)g.W;
      float4 u0 = *(const float4*)(Wf + wi);
      float4 u1 = *(const float4*)(Wf + wi + 4);
      wv[0]=f2s(u0.x); wv[1]=f2s(u0.y); wv[2]=f2s(u0.z); wv[3]=f2s(u0.w);
      wv[4]=f2s(u1.x); wv[5]=f2s(u1.y); wv[6]=f2s(u1.z); wv[7]=f2s(u1.w);
    }
    #pragma unroll
    for (int j = 0; j < 8; j++) Wt[(wn + j)*40 + wk] = wv[j];
    __syncthreads();
    short8 afr = *(const short8*)&As[(wave*16 + m)*40 + kq*8];
    #pragma unroll
    for (int t = 0; t < 4; t++){
      short8 bfr = *(const short8*)&Wt[(t*16 + m)*40 + kq*8];
      acc[t] = __builtin_amdgcn_mfma_f32_16x16x32_bf16(afr, bfr, acc[t], 0, 0, 0);
    }
    __syncthreads();
  }
  #pragma unroll
  for (int t = 0; t < 4; t++){
    int c = col0 + t*16 + m;
    float bv = g.bias ? ldI(g.bias, g.wcol + t*16 + m, f) : 0.f;
    #pragma unroll
    for (int reg = 0; reg < 4; reg++){
      int r = row0 + wave*16 + kq*4 + reg;
      float v = acc[t][reg] + bv;
      if (g.act == 1) v = fmaxf(v, 0.f);
      C[(size_t)r*ldc + c] = f2b(v);
    }
  }
}

// ---------------- GCN aggregation: NPB nodes/block, 8 cols/thread ----------------
template<int NPB, int LPN, typename TO>
__global__ __launch_bounds__(256) void gcn_agg_k(const bf16* __restrict__ G, int ld,
    TO* __restrict__ outp, int ldo,
    const int* __restrict__ offs, const int* __restrict__ srcs,
    const float* __restrict__ enorm, const float* __restrict__ dinv,
    const void* __restrict__ bias, int act, const int* __restrict__ dfp){
  int f = *dfp;
  int g = threadIdx.x / LPN, l = threadIdx.x % LPN;
  int n = blockIdx.x*NPB + g;
  int c = l*8;
  int e0 = offs[n], e1 = offs[n+1];
  float d2 = dinv[n]*dinv[n];
  float acc[8], v[8];
  ld8b(G + (size_t)n*ld + c, v);
  #pragma unroll
  for (int j = 0; j < 8; j++) acc[j] = d2 * v[j];
  for (int e = e0; e < e1; e++){
    int s = srcs[e] & (N-1);
    float nm = enorm[e];
    ld8b(G + (size_t)s*ld + c, v);
    #pragma unroll
    for (int j = 0; j < 8; j++) acc[j] += nm * v[j];
  }
  #pragma unroll
  for (int j = 0; j < 8; j++){
    if (bias) acc[j] += ldI(bias, c + j, f);
    if (act == 1) acc[j] = fmaxf(acc[j], 0.f);
  }
  size_t base = (size_t)n*ldo + c;
  if constexpr (sizeof(TO) == 2){
    uint4 o; o.x = pack2(acc[0],acc[1]); o.y = pack2(acc[2],acc[3]);
    o.z = pack2(acc[4],acc[5]); o.w = pack2(acc[6],acc[7]);
    *(uint4*)((bf16*)outp + base) = o;
  } else {
    float4 o0 = {acc[0],acc[1],acc[2],acc[3]}, o1 = {acc[4],acc[5],acc[6],acc[7]};
    *(float4*)((float*)outp + base) = o0;
    *(float4*)((float*)outp + base + 4) = o1;
  }
}

// ---------------- fused z+r gate aggregation (4 nodes x 64 lanes, 512 cols) ----------------
// cols 0-255: z = sig(sum) -> z_g (f32); cols 256-511: rh = sig(sum)*h -> rh (bf16)
__global__ __launch_bounds__(256) void agg_zr_k(
    const bf16* __restrict__ Gx, const bf16* __restrict__ Gh,
    const int* __restrict__ offs, const int* __restrict__ srcs,
    const float* __restrict__ enorm, const float* __restrict__ dinv,
    const float* __restrict__ hbuf, float* __restrict__ z_g, bf16* __restrict__ rh){
  int g = threadIdx.x >> 6, lane = threadIdx.x & 63;
  int n = blockIdx.x*4 + g;
  int c = lane*8;                       // 0..511
  int e0 = offs[n], e1 = offs[n+1];
  float d2 = dinv[n]*dinv[n];
  float acc[8], v1[8], v2[8];
  ld8b(Gx + (size_t)n*768 + c, v1);
  ld8b(Gh + (size_t)n*1024 + c, v2);
  #pragma unroll
  for (int j = 0; j < 8; j++) acc[j] = d2 * (v1[j] + v2[j]);
  for (int e = e0; e < e1; e++){
    int s = srcs[e] & (N-1);
    float nm = enorm[e];
    ld8b(Gx + (size_t)s*768 + c, v1);
    ld8b(Gh + (size_t)s*1024 + c, v2);
    #pragma unroll
    for (int j = 0; j < 8; j++) acc[j] += nm * (v1[j] + v2[j]);
  }
  if (c < 256){
    size_t base = (size_t)n*HD + c;
    float4 o0, o1;
    o0.x = sigm(acc[0]); o0.y = sigm(acc[1]); o0.z = sigm(acc[2]); o0.w = sigm(acc[3]);
    o1.x = sigm(acc[4]); o1.y = sigm(acc[5]); o1.z = sigm(acc[6]); o1.w = sigm(acc[7]);
    *(float4*)(z_g + base) = o0;
    *(float4*)(z_g + base + 4) = o1;
  } else {
    size_t base = (size_t)n*HD + (c - 256);
    float r[8];
    #pragma unroll
    for (int j = 0; j < 8; j++) r[j] = sigm(acc[j]) * hbuf[base+j];
    uint4 o; o.x = pack2(r[0],r[1]); o.y = pack2(r[2],r[3]);
    o.z = pack2(r[4],r[5]); o.w = pack2(r[6],r[7]);
    *(uint4*)(rh + base) = o;
  }
}

// ---------------- h-update aggregation (8 nodes x 32 lanes) ----------------
__global__ __launch_bounds__(256) void agg_h_k(
    const bf16* __restrict__ G1, const bf16* __restrict__ G2,
    const int* __restrict__ offs, const int* __restrict__ srcs,
    const float* __restrict__ enorm, const float* __restrict__ dinv,
    const float* __restrict__ zgate, float* __restrict__ hbuf, bf16* __restrict__ hbf,
    void* __restrict__ outg, size_t ooff, const int* __restrict__ dfp){
  int f = *dfp;
  int g = threadIdx.x >> 5, l = threadIdx.x & 31;
  int n = blockIdx.x*8 + g;
  int c = l*8;
  int e0 = offs[n], e1 = offs[n+1];
  float d2 = dinv[n]*dinv[n];
  float acc[8], v1[8], v2[8];
  ld8b(G1 + (size_t)n*768 + c, v1);
  ld8b(G2 + (size_t)n*256 + c, v2);
  #pragma unroll
  for (int j = 0; j < 8; j++) acc[j] = d2 * (v1[j] + v2[j]);
  for (int e = e0; e < e1; e++){
    int s = srcs[e] & (N-1);
    float nm = enorm[e];
    ld8b(G1 + (size_t)s*768 + c, v1);
    ld8b(G2 + (size_t)s*256 + c, v2);
    #pragma unroll
    for (int j = 0; j < 8; j++) acc[j] += nm * (v1[j] + v2[j]);
  }
  size_t base = (size_t)n*HD + c;
  #pragma unroll
  for (int j = 0; j < 8; j++){
    float z = zgate[base+j];
    float hv = hbuf[base+j];
    float nv = z*hv + (1.f - z)*tanhf(acc[j]);
    hbuf[base+j] = nv;
    hbf[base+j] = f2b(nv);
    if (outg) stO(outg, ooff + base + j, nv, f);
  }
}

// ---------------- fused enc/prior post + KLD ----------------
__global__ __launch_bounds__(256) void post_k(const float* __restrict__ ms,
    const bf16* __restrict__ Gms, const void* __restrict__ mb, const void* __restrict__ sb,
    const void* __restrict__ eps, size_t eoff, float* __restrict__ z,
    void* __restrict__ outg, size_t em_off, size_t pm_off,
    float* __restrict__ kacc, const int* __restrict__ dfp){
  int f = *dfp;
  int idx = blockIdx.x*256 + threadIdx.x;   // N*ZD
  int tid = threadIdx.x;
  int n = idx >> 6, d = idx & 63;
  float mean = ms[n*128 + d] + ldI(mb, d, f);
  float sd = splus(ms[n*128 + 64 + d] + ldI(sb, d, f));
  z[idx] = ldI(eps, eoff + idx, f) * sd + mean;
  stO(outg, em_off + idx, mean, f);
  float pm = b2f(Gms[n*256 + 128 + d]);
  float ps = splus(b2f(Gms[n*256 + 192 + d]));
  stO(outg, pm_off + idx, pm, f);
  float s1 = sd + 1e-10f, s2 = ps + 1e-10f;
  float dm = mean - pm;
  float el = 2.f*(logf(s2) - logf(s1)) - (s1*s1 + dm*dm)/(s2*s2) + 1.f;
  __shared__ float red[256];
  red[tid] = el; __syncthreads();
  for (int o = 128; o > 0; o >>= 1){ if (tid < o) red[tid] += red[tid+o]; __syncthreads(); }
  if (tid == 0) atomicAdd(kacc, red[0] * (0.5f/((float)N*(float)ZD)));
}

// ---------------- decode + NLL (accumulates tsum/P/Q per t) ----------------
__global__ __launch_bounds__(256, 3) void dec_nll_k(const float* __restrict__ z,
    const void* __restrict__ a, size_t aoff,
    float* __restrict__ pts, float* __restrict__ pP, float* __restrict__ pQ,
    const int* __restrict__ dfp){
  int f = *dfp;
  __shared__ float ziT[64*68];
  __shared__ float zjT[64*68];
  int tid = threadIdx.x;
  int i0 = blockIdx.y*64, j0 = blockIdx.x*64;
  #pragma unroll
  for (int k = 0; k < 16; k++){
    int ii = tid + k*256; int r = ii >> 6, d = ii & 63;
    ziT[d*68 + r] = z[(size_t)(i0+r)*ZD + d];
    zjT[d*68 + r] = z[(size_t)(j0+r)*ZD + d];
  }
  __syncthreads();
  int tx = tid & 15, ty = tid >> 4;
  float acc[4][4] = {};
  #pragma unroll 8
  for (int d = 0; d < 64; d++){
    float4 ra = *(const float4*)&ziT[d*68 + ty*4];
    float4 rb = *(const float4*)&zjT[d*68 + tx*4];
    acc[0][0] += ra.x*rb.x; acc[0][1] += ra.x*rb.y; acc[0][2] += ra.x*rb.z; acc[0][3] += ra.x*rb.w;
    acc[1][0] += ra.y*rb.x; acc[1][1] += ra.y*rb.y; acc[1][2] += ra.y*rb.z; acc[1][3] += ra.y*rb.w;
    acc[2][0] += ra.z*rb.x; acc[2][1] += ra.z*rb.y; acc[2][2] += ra.z*rb.z; acc[2][3] += ra.z*rb.w;
    acc[3][0] += ra.w*rb.x; acc[3][1] += ra.w*rb.y; acc[3][2] += ra.w*rb.z; acc[3][3] += ra.w*rb.w;
  }
  float lts = 0.f, lP = 0.f, lQ = 0.f;
  #pragma unroll
  for (int p = 0; p < 4; p++){
    int i = i0 + ty*4 + p;
    size_t rowoff = aoff + (size_t)i*N + j0 + tx*4;
    float av4[4];
    if (f){
      float4 v = *(const float4*)((const float*)a + rowoff);
      av4[0] = v.x; av4[1] = v.y; av4[2] = v.z; av4[3] = v.w;
    } else {
      const bf16* pb = (const bf16*)a + rowoff;
      av4[0] = b2f(pb[0]); av4[1] = b2f(pb[1]); av4[2] = b2f(pb[2]); av4[3] = b2f(pb[3]);
    }
    #pragma unroll
    for (int q = 0; q < 4; q++){
      float dec = sigm(acc[p][q]);
      float av = av4[q];
      lts += av;
      lQ += (1.f - av)*log1pf(expf(dec));
      if (av != 0.f) lP += av*log1pf(expf(-dec));
    }
  }
  __syncthreads();
  ziT[tid] = lts; __syncthreads();
  for (int o = 128; o > 0; o >>= 1){ if (tid < o) ziT[tid] += ziT[tid+o]; __syncthreads(); }
  if (tid == 0) atomicAdd(pts, ziT[0]);
  __syncthreads();
  ziT[tid] = lP; __syncthreads();
  for (int o = 128; o > 0; o >>= 1){ if (tid < o) ziT[tid] += ziT[tid+o]; __syncthreads(); }
  if (tid == 0) atomicAdd(pP, ziT[0]);
  __syncthreads();
  ziT[tid] = lQ; __syncthreads();
  for (int o = 128; o > 0; o >>= 1){ if (tid < o) ziT[tid] += ziT[tid+o]; __syncthreads(); }
  if (tid == 0) atomicAdd(pQ, ziT[0]);
}

__global__ void finalize_k(const float* __restrict__ scal, void* __restrict__ outg,
                           const int* __restrict__ dfp){
  if (threadIdx.x == 0){
    int f = *dfp;
    const float NNf = 16777216.f;
    float nll = 0.f;
    for (int t = 0; t < T_STEPS; t++){
      float ts = scal[8+t], P = scal[12+t], Q = scal[16+t];
      float posw = (NNf - ts)/ts;
      nll += (posw*P + Q) * 0.5f/(NNf - ts);
    }
    stO(outg, 0, scal[4], f);
    stO(outg, 1, nll, f);
  }
}

// ---------------- host ----------------
extern "C" void kernel_launch(void* const* d_in, const int* in_sizes, int n_in,
                              void* d_out, int out_size, void* d_ws, size_t ws_size,
                              hipStream_t stream){
  const void* x           = d_in[0];
  const int*  ei          = (const int*)d_in[1];
  const void* adj         = d_in[2];
  const void* eps         = d_in[3];
  const void* h0          = d_in[4];
  const void* phi_x_w     = d_in[5];
  const void* phi_x_b     = d_in[6];
  const void* phi_z_w     = d_in[7];
  const void* phi_z_b     = d_in[8];
  const void* enc_w       = d_in[9];
  const void* enc_b       = d_in[10];
  const void* enc_mean_w  = d_in[11];
  const void* enc_mean_b  = d_in[12];
  const void* enc_std_w   = d_in[13];
  const void* enc_std_b   = d_in[14];
  const void* prior_w     = d_in[15];
  const void* prior_b     = d_in[16];
  const void* prior_mean_w= d_in[17];
  const void* prior_mean_b= d_in[18];
  const void* prior_std_w = d_in[19];
  const void* prior_std_b = d_in[20];
  const void* gru_xz_w    = d_in[21];
  const void* gru_hz_w    = d_in[22];
  const void* gru_xr_w    = d_in[23];
  const void* gru_hr_w    = d_in[24];
  const void* gru_xh_w    = d_in[25];
  const void* gru_hh_w    = d_in[26];

  // bump allocator over d_ws (~50 MB total)
  char* wp = (char*)d_ws;
  auto alloc = [&](size_t bytes){ void* p = (void*)wp; wp += (bytes + 255) & ~(size_t)255; return p; };
  float* scal  = (float*)alloc(64*sizeof(float));          // [4]=kld, [8+t]=ts, [12+t]=P, [16+t]=Q
  int*   dflag = (int*)  alloc(256);
  float* dinv  = (float*)alloc((size_t)T_STEPS*N*4);
  int*   offs  = (int*)  alloc((size_t)T_STEPS*(N+1)*4);
  int*   srcs  = (int*)  alloc((size_t)T_STEPS*E*4);
  float* enorm = (float*)alloc((size_t)T_STEPS*E*4);
  int*   deg   = (int*)  alloc((size_t)T_STEPS*N*4);       // reused as scatter cursor
  float* h_prev= (float*)alloc((size_t)N*HD*4);
  bf16*  h_bf  = (bf16*) alloc((size_t)N*HD*2);
  bf16*  phiXa = (bf16*) alloc((size_t)T_STEPS*N*HD*2);    // all steps
  bf16*  Tb1   = (bf16*) alloc((size_t)N*HD*2);            // enc_t, later rh
  bf16*  Tb2   = (bf16*) alloc((size_t)N*HD*2);            // phiZ
  float* zbuf  = (float*)alloc((size_t)N*ZD*4);
  float* ms    = (float*)alloc((size_t)N*128*4);           // enc agg [mean|std] f32
  float* z_g   = (float*)alloc((size_t)N*HD*4);
  bf16*  Gs1   = (bf16*) alloc((size_t)N*1024*2);          // group1: enc_pre|prior_t|hz|hr
  bf16*  Gsx   = (bf16*) alloc((size_t)N*768*2);           // gru-x: xz|xr|xh
  bf16*  Gms   = (bf16*) alloc((size_t)N*256*2);           // group2: enc_ms|prior_ms
  bf16*  Gh2   = (bf16*) alloc((size_t)N*256*2);           // hh staging

  detect_k<<<1,64,0,stream>>>(x, dflag);
  zero_f32_k<<<1,64,0,stream>>>(scal);
  zero_i32_k<<<(T_STEPS*N)/256,256,0,stream>>>(deg, T_STEPS*N);
  count_deg_k<<<(T_STEPS*E)/256,256,0,stream>>>(ei, deg);
  scan_k<<<T_STEPS,256,0,stream>>>(deg, offs, dinv);
  init_cursor_k<<<(T_STEPS*N)/256,256,0,stream>>>(deg, offs);
  scatter_k<<<(T_STEPS*E)/256,256,0,stream>>>(ei, deg, srcs, enorm, dinv);
  ld_copy2_k<<<(N*HD)/256,256,0,stream>>>(h0, h_prev, h_bf, N*HD, dflag);

  auto multi = [&](const GDs& gg, int M, bf16* C, int ldc){
    dim3 g(M/64, N/64);
    gemm_multi_k<<<g,256,0,stream>>>(gg, C, ldc, dflag);
  };

  const size_t OUT_EM = 2;
  const size_t OUT_PM = 2 + (size_t)T_STEPS*N*ZD;
  const size_t OUT_H  = 2 + (size_t)2*T_STEPS*N*ZD;

  // phi_x for ALL steps: relu(x @ phi_x_w + b) -> phiXa  [T*N x 256]
  {
    dim3 g(HD/64, (T_STEPS*N)/64);
    gemm_k<<<g,256,0,stream>>>(x, 1, 0, XD, nullptr, 0, 0, 0, XD, XD,
        phi_x_w, nullptr, nullptr, HD, phiXa, HD, 1, phi_x_b, nullptr, nullptr, 1, dflag);
  }

  for (int t = 0; t < T_STEPS; t++){
    const bf16* phiX = phiXa + (size_t)t*N*HD;
    const int* offs_t = offs + t*(N+1);
    const int* srcs_t = srcs + (size_t)t*E;
    const float* en_t = enorm + (size_t)t*E;
    const float* dv_t = dinv + t*N;

    // group1: M=1024 -> Gs1: [enc_pre | prior_t | hz | hr]
    {
      GDs gg{};
      for (int i = 0; i < 4; i++)
        gg.d[i]    = { phiX, h_bf, HD, HD, enc_w,    HD, 64*i, nullptr, 0,   512, 0 };
      for (int i = 0; i < 4; i++)
        gg.d[4+i]  = { nullptr, h_bf, 0, HD, prior_w, HD, 64*i, prior_b, 256, 512, 1 };
      for (int i = 0; i < 4; i++)
        gg.d[8+i]  = { nullptr, h_bf, 0, HD, gru_hz_w, HD, 64*i, nullptr, 256, 512, 0 };
      for (int i = 0; i < 4; i++)
        gg.d[12+i] = { nullptr, h_bf, 0, HD, gru_hr_w, HD, 64*i, nullptr, 256, 512, 0 };
      multi(gg, 1024, Gs1, 1024);
    }
    // enc aggregation: relu(agg(enc_pre)+b) -> Tb1
    gcn_agg_k<8,32,bf16><<<N/8,256,0,stream>>>(Gs1, 1024, Tb1, HD, offs_t, srcs_t,
        en_t, dv_t, enc_b, 1, dflag);
    // group2: M=256 -> Gms: [enc_mean|enc_std|prior_mean|prior_std] (prior biases applied)
    {
      GDs gg{};
      gg.d[0] = { Tb1, nullptr, HD, 0, enc_mean_w,  ZD, 0, nullptr, 0, 256, 0 };
      gg.d[1] = { Tb1, nullptr, HD, 0, enc_std_w,   ZD, 0, nullptr, 0, 256, 0 };
      gg.d[2] = { Gs1 + 256, nullptr, 1024, 0, prior_mean_w, ZD, 0, prior_mean_b, 0, 256, 0 };
      gg.d[3] = { Gs1 + 256, nullptr, 1024, 0, prior_std_w,  ZD, 0, prior_std_b,  0, 256, 0 };
      multi(gg, 256, Gms, 256);
    }
    // enc mean/std aggregation -> ms (f32)
    gcn_agg_k<16,16,float><<<N/16,256,0,stream>>>(Gms, 256, ms, 128, offs_t, srcs_t,
        en_t, dv_t, nullptr, 0, dflag);
    // fused post: z, out_em, out_pm, kld
    post_k<<<(N*ZD)/256,256,0,stream>>>(ms, Gms, enc_mean_b, enc_std_b,
        eps, (size_t)t*N*ZD, zbuf, d_out, OUT_EM + (size_t)t*N*ZD,
        OUT_PM + (size_t)t*N*ZD, scal + 4, dflag);
    // phi_z = relu(z @ phi_z_w + b) -> Tb2
    {
      dim3 g(HD/64, N/64);
      gemm_k<<<g,256,0,stream>>>(zbuf, 0, 0, ZD, nullptr, 0, 0, 0, ZD, ZD,
          phi_z_w, nullptr, nullptr, HD, Tb2, HD, 1, phi_z_b, nullptr, nullptr, 1, dflag);
    }
    // decode + NLL (accumulates ts/P/Q)
    dec_nll_k<<<dim3(64,64),256,0,stream>>>(zbuf, adj, (size_t)t*N*N,
        scal + 8 + t, scal + 12 + t, scal + 16 + t, dflag);
    // gru-x: [phiX|phiZ] @ {xz|xr|xh} -> Gsx (M=768)
    {
      GDs gg{};
      for (int i = 0; i < 4; i++)
        gg.d[i]   = { phiX, Tb2, HD, HD, gru_xz_w, HD, 64*i, nullptr, 0, 512, 0 };
      for (int i = 0; i < 4; i++)
        gg.d[4+i] = { phiX, Tb2, HD, HD, gru_xr_w, HD, 64*i, nullptr, 0, 512, 0 };
      for (int i = 0; i < 4; i++)
        gg.d[8+i] = { phiX, Tb2, HD, HD, gru_xh_w, HD, 64*i, nullptr, 0, 512, 0 };
      multi(gg, 768, Gsx, 768);
    }
    // fused z+r gates
    agg_zr_k<<<N/4,256,0,stream>>>(Gsx, Gs1 + 512, offs_t, srcs_t, en_t, dv_t,
                                   h_prev, z_g, Tb1);
    // candidate staging: rh @ hh_w -> Gh2
    {
      GDs gg{};
      for (int i = 0; i < 4; i++)
        gg.d[i] = { Tb1, nullptr, HD, 0, gru_hh_w, HD, 64*i, nullptr, 0, 256, 0 };
      multi(gg, 256, Gh2, 256);
    }
    // h update
    agg_h_k<<<N/8,256,0,stream>>>(Gsx + 512, Gh2, offs_t, srcs_t, en_t, dv_t,
        z_g, h_prev, h_bf, (t == T_STEPS-1) ? d_out : (void*)nullptr, OUT_H, dflag);
  }
  finalize_k<<<1,64,0,stream>>>(scal, d_out, dflag);
}